// Round 2
// baseline (728.513 us; speedup 1.0000x reference)
//
#include <hip/hip_runtime.h>
#include <cstdint>
#include <cstddef>

// ---------------------------------------------------------------------------
// Residual VQ (SoundStream Alg.1) on MI355X — R5: occupancy doubling.
// R4 (582 us k_main) was latency-bound: Occupancy 22.6% (2 waves/SIMD),
// VALUBusy 21%, MfmaUtil 10% -> no pipe saturated, everything exposed.
// R5 = same algorithm/numerics, restructured to 1024 thr (16 waves, 4/SIMD):
//  - wave owns 64 codes (acc[2][2] = 64 regs, was 128); 16 thr/point
//    (r4[8] = 32 regs, was 64) -> total <=128/wave so 4 waves/SIMD fit
//  - cross-q staging: next q's chunks 0/1 issued at ks=30/31 of current
//    K-loop; q=0 prologue staged before A-build (fetch hides under cvt)
//  - candidate margin / tier-1 / tier-2 exact-refinement logic UNCHANGED
//    (emitted indices remain exact-arithmetic argmin, as verified R3/R4)
// ---------------------------------------------------------------------------

#define BATCH 8
#define SEQ   2048
#define DIM   512
#define NUMQ  8
#define CODES 1024
#define NPTS  (BATCH*SEQ)            // 16384
#define MPTS  64                     // points per workgroup
#define NWG   (NPTS/MPTS)            // 256 = 1 WG per CU
#define NTHR  1024                   // 16 waves
#define NW    16
#define NCHUNK 32                    // K-steps of 16 per quantizer
#define CHUNK_BYTES 32768            // [g:2][code:1024][8 f16] = 32 KB

#define OUT_IDX   (BATCH*SEQ*DIM)             // 8388608
#define OUT_LOSS  (OUT_IDX + BATCH*SEQ*NUMQ)  // 8519680

#define WS_LOSS   0                           // 8 doubles
#define WS_CNORM  1024                        // 8192 floats
#define WS_CBH    40960                       // f16 chunk images, 8.39 MB

typedef _Float16 f16x8  __attribute__((ext_vector_type(8)));
typedef _Float16 f16x4  __attribute__((ext_vector_type(4)));
typedef float    f32x16 __attribute__((ext_vector_type(16)));

__global__ void k_zero(double* loss) {
  if (threadIdx.x < NUMQ) loss[threadIdx.x] = 0.0;
}

// per-code squared norm (fp32; only feeds the approximate scores)
__global__ void k_cnorm(const float* __restrict__ cb, float* __restrict__ cnorm) {
  int r = blockIdx.x * blockDim.x + threadIdx.x;      // 0..8191
  const float* row = cb + (size_t)r * DIM;
  float s = 0.f;
  for (int d = 0; d < DIM; d += 4) {
    float4 v = *(const float4*)(row + d);
    s += v.x * v.x + v.y * v.y + v.z * v.z + v.w * v.w;
  }
  cnorm[r] = s;
}

// Build f16 codebook chunk images. Chunk (q,ks) image (32 KB, linear):
//   byte = g*16384 + c*16 + j*2  holds  f16(cb[q][c][ks*16 + g*8 + j])
__global__ void k_prep(const float* __restrict__ cb, unsigned char* __restrict__ cbH) {
  unsigned tid = blockIdx.x * blockDim.x + threadIdx.x;   // 0..1048575 (8B units)
  unsigned h  = tid & 1;
  unsigned r  = tid >> 1;
  unsigned c  = r & (CODES - 1);
  unsigned t2 = r >> 10;
  unsigned g  = t2 & 1;
  unsigned t3 = t2 >> 1;
  unsigned ks = t3 & 31;
  unsigned q  = t3 >> 5;
  unsigned k  = ks * 16 + g * 8 + h * 4;
  float4 v = *(const float4*)(cb + ((size_t)((q << 10) | c)) * DIM + k);
  f16x4 o;
  o[0] = (_Float16)v.x; o[1] = (_Float16)v.y; o[2] = (_Float16)v.z; o[3] = (_Float16)v.w;
  *(f16x4*)(cbH + (size_t)tid * 8) = o;
}

// issue one 32 KB chunk stage (2x global_load_lds dwordx4 per thread @1024thr)
__device__ __forceinline__ void stage(const unsigned char* __restrict__ cbq, int ks,
                                      unsigned char* buf, int tid) {
  const unsigned char* src = cbq + (size_t)ks * CHUNK_BYTES + tid * 16;
  unsigned char* dst = buf + (tid & ~63) * 16;   // wave-uniform base; HW adds lane*16
  #pragma unroll
  for (int i = 0; i < 2; ++i)
    __builtin_amdgcn_global_load_lds(
        (const __attribute__((address_space(1))) void*)(src + i * 16384),
        (__attribute__((address_space(3))) void*)(dst + i * 16384), 16, 0, 0);
}

__launch_bounds__(NTHR, 4)
__global__ void k_main(const float* __restrict__ x, const float* __restrict__ cb,
                       const unsigned char* __restrict__ cbH,
                       const float* __restrict__ cnorm,
                       double* __restrict__ lossAcc,
                       float* __restrict__ out)
{
  // A-plane: f16 resid, row m (64) x 512 k. 16B slot s=k/8 stored at
  // slot' = swap3(s) ^ (m&31) -> conflict-free b128 reads and writes.
  __shared__ __align__(16) unsigned char Af[MPTS * DIM * 2];      // 64 KB
  __shared__ __align__(16) unsigned char Bb[2][CHUNK_BYTES];      // 64 KB
  __shared__ float          s1w[MPTS][NW];
  __shared__ unsigned short id1w[MPTS][NW];
  __shared__ unsigned short cand[MPTS][NW][4];
  __shared__ unsigned char  ccnt[MPTS][NW];
  __shared__ float          gmA[MPTS];
  __shared__ int            win0A[MPTS];
  __shared__ unsigned short idxs[MPTS][NUMQ];
  __shared__ double         lred[NW];

  const int tid = threadIdx.x;
  const int cl  = tid & 63;
  const int w   = tid >> 6;          // wave 0..15
  const int l31 = cl & 31;
  const int l5  = cl >> 5;           // k-group within wave
  const int wg  = blockIdx.x;

  // residual registers: thread owns point rp = tid>>4, dims rj*32 .. +32
  const int rp = tid >> 4;
  const int rj = tid & 15;
  const size_t gp = (size_t)wg * MPTS + rp;
  float4 r4[8];
  {
    const float4* xr = (const float4*)(x + gp * DIM + rj * 32);
    #pragma unroll
    for (int i = 0; i < 8; ++i) r4[i] = xr[i];
  }

  // B frag byte base (within buf): wave w owns codes w*64 .. w*64+63
  const int bBase = l5 * 16384 + (w * 64 + l31) * 16;

  for (int q = 0; q < NUMQ; ++q) {
    const unsigned char* cbq = cbH + (size_t)q * NCHUNK * CHUNK_BYTES;
    if (q == 0) {                       // prologue fetch hides under A-build
      stage(cbq, 0, Bb[0], tid);
      stage(cbq, 1, Bb[1], tid);
    }
    // ---- A-plane build: f16(resid), swizzled
    #pragma unroll
    for (int i = 0; i < 4; ++i) {
      float4 a = r4[2 * i], b = r4[2 * i + 1];
      f16x8 v;
      v[0] = (_Float16)a.x; v[1] = (_Float16)a.y; v[2] = (_Float16)a.z; v[3] = (_Float16)a.w;
      v[4] = (_Float16)b.x; v[5] = (_Float16)b.y; v[6] = (_Float16)b.z; v[7] = (_Float16)b.w;
      const int s = rj * 4 + i;                        // logical slot = k/8
      const int sl = (((s & 7) << 3) | (s >> 3)) ^ (rp & 31);
      *(f16x8*)(Af + rp * 1024 + (sl << 4)) = v;
    }
    __syncthreads();

    f32x16 acc[2][2];
    #pragma unroll
    for (int mt = 0; mt < 2; ++mt)
      #pragma unroll
      for (int nt = 0; nt < 2; ++nt)
        #pragma unroll
        for (int e = 0; e < 16; ++e) acc[mt][nt][e] = 0.0f;

    // ---- MFMA K-loop: counted vmcnt, raw barriers, cross-q dbuf staging
    #pragma unroll 1
    for (int ks = 0; ks < NCHUNK; ++ks) {
      if (q == NUMQ - 1 && ks == NCHUNK - 1)
        asm volatile("s_waitcnt vmcnt(0)" ::: "memory");
      else
        asm volatile("s_waitcnt vmcnt(2)" ::: "memory");
      __builtin_amdgcn_s_barrier();                    // chunk ks fully staged
      const unsigned char* bufp = Bb[ks & 1];
      const int s5 = (ks << 1) | l5;
      const int sf = ((((s5 & 7) << 3) | (s5 >> 3)) ^ l31) << 4;
      f16x8 a0 = *(const f16x8*)(Af + l31 * 1024 + sf);
      f16x8 a1 = *(const f16x8*)(Af + 32768 + l31 * 1024 + sf);
      f16x8 b0 = *(const f16x8*)(bufp + bBase);
      f16x8 b1 = *(const f16x8*)(bufp + bBase + 512);  // +32 codes
      __builtin_amdgcn_s_setprio(1);
      acc[0][0] = __builtin_amdgcn_mfma_f32_32x32x16_f16(a0, b0, acc[0][0], 0, 0, 0);
      acc[0][1] = __builtin_amdgcn_mfma_f32_32x32x16_f16(a0, b1, acc[0][1], 0, 0, 0);
      acc[1][0] = __builtin_amdgcn_mfma_f32_32x32x16_f16(a1, b0, acc[1][0], 0, 0, 0);
      acc[1][1] = __builtin_amdgcn_mfma_f32_32x32x16_f16(a1, b1, acc[1][1], 0, 0, 0);
      __builtin_amdgcn_s_setprio(0);
      asm volatile("s_waitcnt lgkmcnt(0)" ::: "memory");
      __builtin_amdgcn_s_barrier();                    // all reads of buf done
      const int nid = ks + 2;
      if (nid < NCHUNK) stage(cbq, nid, Bb[ks & 1], tid);
      else if (q + 1 < NUMQ)
        stage(cbq + (size_t)NCHUNK * CHUNK_BYTES, nid - NCHUNK, Bb[ks & 1], tid);
    }

    // ---- scores = -2*dot + ||c||^2 (approximate; f16-rounded inputs)
    {
      const float* cnq = cnorm + (q << 10) + (w << 6) + l31;
      const float cn0 = cnq[0], cn1 = cnq[32];
      #pragma unroll
      for (int mt = 0; mt < 2; ++mt) {
        acc[mt][0] = acc[mt][0] * -2.0f + cn0;
        acc[mt][1] = acc[mt][1] * -2.0f + cn1;
      }
    }

    // ---- pass 1: per-wave per-point top-1 (over this wave's 64 codes)
    // C/D layout 32x32: col = lane&31, row = (r&3)+8*(r>>2)+4*(lane>>5)
    #pragma unroll
    for (int mt = 0; mt < 2; ++mt)
      #pragma unroll
      for (int r = 0; r < 16; ++r) {
        float s = acc[mt][0][r]; int bi = l31;
        if (acc[mt][1][r] < s) { s = acc[mt][1][r]; bi = 32 + l31; }
        #pragma unroll
        for (int m = 1; m < 32; m <<= 1) {
          float os = __shfl_xor(s, m); int ob = __shfl_xor(bi, m);
          if (os < s || (os == s && ob < bi)) { s = os; bi = ob; }
        }
        if (l31 == 0) {
          int p = mt * 32 + (r & 3) + 8 * (r >> 2) + 4 * l5;
          s1w[p][w] = s; id1w[p][w] = (unsigned short)bi;
        }
      }
    __syncthreads();

    // ---- pass 2: global min + provisional winner per point
    if (tid < MPTS) {
      int p = tid;
      float bs = s1w[p][0]; int bi = id1w[p][0];
      #pragma unroll
      for (int ww = 1; ww < NW; ++ww) {
        float s = s1w[p][ww];
        if (s < bs) { bs = s; bi = ww * 64 + id1w[p][ww]; }
      }
      gmA[p] = bs; win0A[p] = bi;
    }
    __syncthreads();

    // ---- pass 3: ballot candidates within margin of global min (UNCHANGED
    //      margin: f16 score error sigma~0.03, margin 1.5 proven in R4)
    #pragma unroll
    for (int mt = 0; mt < 2; ++mt)
      #pragma unroll
      for (int r = 0; r < 16; ++r) {
        const int p0 = mt * 32 + (r & 3) + 8 * (r >> 2);
        const float g0 = gmA[p0], g1 = gmA[p0 + 4];
        const float lim0 = g0 + 1.5f + 1e-4f * fabsf(g0);
        const float lim1 = g1 + 1.5f + 1e-4f * fabsf(g1);
        const float lim = l5 ? lim1 : lim0;
        unsigned long long b0 = __ballot(acc[mt][0][r] <= lim);
        unsigned long long b1 = __ballot(acc[mt][1][r] <= lim);
        if (cl == 0 || cl == 32) {
          const int p = p0 + (cl >> 3);                // cl=32 -> p0+4
          unsigned short* cd = &cand[p][w][0];
          unsigned m0 = (cl == 0) ? (unsigned)b0 : (unsigned)(b0 >> 32);
          unsigned m1 = (cl == 0) ? (unsigned)b1 : (unsigned)(b1 >> 32);
          int n = 0;
          while (m0 && n < 4) { int bt = __builtin_ctz(m0); m0 &= m0 - 1; cd[n++] = (unsigned short)bt; }
          while (m1 && n < 4) { int bt = __builtin_ctz(m1); m1 &= m1 - 1; cd[n++] = (unsigned short)(32 + bt); }
          ccnt[p][w] = (unsigned char)n;
        }
      }
    __syncthreads();

    // ---- pass 4: refinement tiers (wave w owns points w*4..w*4+3; their
    //      fp32 residual lives in this wave's r4 registers, 16 lanes/point)
    #pragma unroll 1
    for (int pp = 0; pp < 4; ++pp) {
      const int p = w * 4 + pp;
      int tot = 0;
      #pragma unroll
      for (int ww = 0; ww < NW; ++ww) tot += ccnt[p][ww];
      int winner;
      if (tot <= 1) {
        winner = win0A[p];
      } else {
        const size_t gpp = (size_t)wg * MPTS + p;
        // tier 1: fp64 dot vs exact fp32 residual (in regs)
        double bs = 1.0e300, bs2 = 1.0e300; int bi = 0x7FFFFFFF;
        #pragma unroll 1
        for (int ww = 0; ww < NW; ++ww) {
          const int nn = ccnt[p][ww];
          #pragma unroll 1
          for (int si = 0; si < nn; ++si) {
            const int cc = ww * 64 + cand[p][ww][si];
            const float4* cr = (const float4*)(cb + ((size_t)q * CODES + cc) * DIM + (cl & 15) * 32);
            double dt = 0.0, cs = 0.0;
            #pragma unroll
            for (int i = 0; i < 8; ++i) {
              float4 cv = cr[i];
              dt += (double)r4[i].x * cv.x + (double)r4[i].y * cv.y
                  + (double)r4[i].z * cv.z + (double)r4[i].w * cv.w;
              cs += (double)cv.x * cv.x + (double)cv.y * cv.y
                  + (double)cv.z * cv.z + (double)cv.w * cv.w;
            }
            #pragma unroll
            for (int m = 1; m < 16; m <<= 1) { dt += __shfl_xor(dt, m); cs += __shfl_xor(cs, m); }
            double dtb = __shfl(dt, pp * 16), csb = __shfl(cs, pp * 16);
            double s = -2.0 * dtb + csb;
            if (s < bs) { bs2 = bs; bs = s; bi = cc; }
            else if (s < bs2) { bs2 = s; }
          }
        }
        // tier 2: exact fp64 chain rebuild from x (rare: <1e-3 gap)
        if (bs2 - bs <= 1e-3 + 1e-6 * fabs(bs)) {
          bs = 1.0e300; bi = 0x7FFFFFFF;
          const float4* xr2 = (const float4*)(x + gpp * DIM + (cl & 15) * 32);
          #pragma unroll 1
          for (int ww = 0; ww < NW; ++ww) {
            const int nn = ccnt[p][ww];
            #pragma unroll 1
            for (int si = 0; si < nn; ++si) {
              const int cc = ww * 64 + cand[p][ww][si];
              const float4* cr = (const float4*)(cb + ((size_t)q * CODES + cc) * DIM + (cl & 15) * 32);
              double dt = 0.0, cs = 0.0;
              #pragma unroll 1
              for (int i = 0; i < 8; ++i) {
                float4 xv = xr2[i];
                double rhx = xv.x, rhy = xv.y, rhz = xv.z, rhw = xv.w;
                #pragma unroll 1
                for (int t2 = 0; t2 < q; ++t2) {
                  const float4* qr = (const float4*)(cb + ((size_t)t2 * CODES + idxs[p][t2]) * DIM + (cl & 15) * 32);
                  float4 qv = qr[i];
                  rhx -= (double)qv.x; rhy -= (double)qv.y;
                  rhz -= (double)qv.z; rhw -= (double)qv.w;
                }
                float4 cv = cr[i];
                dt += rhx * cv.x + rhy * cv.y + rhz * cv.z + rhw * cv.w;
                cs += (double)cv.x * cv.x + (double)cv.y * cv.y
                    + (double)cv.z * cv.z + (double)cv.w * cv.w;
              }
              #pragma unroll
              for (int m = 1; m < 16; m <<= 1) { dt += __shfl_xor(dt, m); cs += __shfl_xor(cs, m); }
              double dtb = __shfl(dt, pp * 16), csb = __shfl(cs, pp * 16);
              double s = -2.0 * dtb + csb;
              if (s < bs || (s == bs && cc < bi)) { bs = s; bi = cc; }
            }
          }
        }
        winner = bi;
      }
      if (cl == 0) idxs[p][q] = (unsigned short)winner;
    }

    // ---- pass 5: residual update (exact fp32 chain) + commit loss (fp64)
    {
      const int win = idxs[rp][q];
      const float4* cr = (const float4*)(cb + ((size_t)q * CODES + win) * DIM + rj * 32);
      double ls = 0.0;
      #pragma unroll
      for (int i = 0; i < 8; ++i) {
        float4 cv = cr[i];
        float dx = cv.x - r4[i].x, dy = cv.y - r4[i].y;
        float dz = cv.z - r4[i].z, dw = cv.w - r4[i].w;
        ls += (double)dx * dx + (double)dy * dy + (double)dz * dz + (double)dw * dw;
        r4[i].x -= cv.x; r4[i].y -= cv.y; r4[i].z -= cv.z; r4[i].w -= cv.w;
      }
      #pragma unroll
      for (int m = 1; m < 64; m <<= 1) ls += __shfl_xor(ls, m);
      if (cl == 0) lred[w] = ls;
      __syncthreads();
      if (tid == 0) {
        double t = 0.0;
        #pragma unroll
        for (int ww = 0; ww < NW; ++ww) t += lred[ww];
        atomicAdd(lossAcc + q, t);
      }
      __syncthreads();
    }
  } // q

  // ---- outputs: quantized = x - resid_final; indices as float
  {
    const float4* xr = (const float4*)(x + gp * DIM + rj * 32);
    float4* orow = (float4*)(out + gp * DIM + rj * 32);
    #pragma unroll
    for (int i = 0; i < 8; ++i) {
      float4 xv = xr[i];
      float4 o;
      o.x = xv.x - r4[i].x; o.y = xv.y - r4[i].y;
      o.z = xv.z - r4[i].z; o.w = xv.w - r4[i].w;
      orow[i] = o;
    }
  }
  if (tid < MPTS) {
    float* ob = out + OUT_IDX + ((size_t)wg * MPTS + tid) * NUMQ;
    #pragma unroll
    for (int j = 0; j < NUMQ; ++j) ob[j] = (float)idxs[tid][j];
  }
}

__global__ void k_fin(const double* __restrict__ loss, float* __restrict__ out) {
  int t = threadIdx.x;
  if (t < NUMQ)
    out[OUT_LOSS + t] = (float)(loss[t] / (double)((size_t)BATCH * SEQ * DIM));
}

extern "C" void kernel_launch(void* const* d_in, const int* in_sizes, int n_in,
                              void* d_out, int out_size, void* d_ws, size_t ws_size,
                              hipStream_t stream) {
  (void)in_sizes; (void)n_in; (void)out_size; (void)ws_size;
  const float* x  = (const float*)d_in[0];
  const float* cb = (const float*)d_in[1];
  float* out = (float*)d_out;
  char* ws = (char*)d_ws;
  double* loss = (double*)(ws + WS_LOSS);
  float* cnorm = (float*)(ws + WS_CNORM);
  unsigned char* cbH = (unsigned char*)(ws + WS_CBH);   // 8.39 MB

  k_zero<<<1, 64, 0, stream>>>(loss);
  k_cnorm<<<NUMQ * CODES / 256, 256, 0, stream>>>(cb, cnorm);
  k_prep<<<NUMQ * NCHUNK * CHUNK_BYTES / 8 / 256, 256, 0, stream>>>(cb, cbH);
  k_main<<<NWG, NTHR, 0, stream>>>(x, cb, cbH, cnorm, loss, out);
  k_fin<<<1, 64, 0, stream>>>(loss, out);
}

// Round 3
// 632.073 us; speedup vs baseline: 1.1526x; 1.1526x over previous
//
#include <hip/hip_runtime.h>
#include <cstdint>
#include <cstddef>

// ---------------------------------------------------------------------------
// Residual VQ (SoundStream Alg.1) on MI355X — R6: barrier-free K-loop.
// R5 post-mortem: 1024-thr/4-wave-per-SIMD forced 64 arch VGPRs -> 25+ MB of
// scratch spills (WRITE 59->134 MB), net regression 582->669. Reverted to the
// R4 structure (512 thr, 64 pts, acc[2][4], 2 waves/SIMD) whose counters show
// no pipe >25% busy -> the missing time is lockstep-barrier serialization
// (2 barriers x 256 K-steps over one 8-wave domain) plus a vmcnt over-wait
// (staged 4 loads, waited vmcnt(2)).
// R6: codebook image re-laid per-wave: each wave stages only ITS 128 codes
// (4 KB/chunk) into wave-PRIVATE LDS slots -> K-loop has ZERO barriers; vmcnt
// is per-wave exact (vmcnt(4) steady state, FIFO retirement argument); slot
// overwrite guarded by own-wave lgkmcnt(0). Cross-q staging keeps the pipe
// full through the epilogue. A-plane build + all epilogue passes + exactness
// tiers are verbatim R4 (proven numerics, absmax 0.03125).
// ---------------------------------------------------------------------------

#define BATCH 8
#define SEQ   2048
#define DIM   512
#define NUMQ  8
#define CODES 1024
#define NPTS  (BATCH*SEQ)            // 16384
#define MPTS  64                     // points per workgroup
#define NWG   (NPTS/MPTS)            // 256 = 1 WG per CU
#define NTHR  512                    // 8 waves
#define NCHUNK 32                    // K-steps of 16 per quantizer
#define NCHUNK_TOT (NUMQ*NCHUNK)     // 256 global chunks
#define CHUNK_BYTES 32768            // per global chunk: [w:8][g:2][c:128][j:8 f16]

#define OUT_IDX   (BATCH*SEQ*DIM)             // 8388608
#define OUT_LOSS  (OUT_IDX + BATCH*SEQ*NUMQ)  // 8519680

#define WS_LOSS   0                           // 8 doubles
#define WS_CNORM  1024                        // 8192 floats
#define WS_CBH    40960                       // f16 chunk images, 8.39 MB

typedef _Float16 f16x8  __attribute__((ext_vector_type(8)));
typedef _Float16 f16x4  __attribute__((ext_vector_type(4)));
typedef float    f32x16 __attribute__((ext_vector_type(16)));

__global__ void k_zero(double* loss) {
  if (threadIdx.x < NUMQ) loss[threadIdx.x] = 0.0;
}

// per-code squared norm (fp32; only feeds the approximate scores)
__global__ void k_cnorm(const float* __restrict__ cb, float* __restrict__ cnorm) {
  int r = blockIdx.x * blockDim.x + threadIdx.x;      // 0..8191
  const float* row = cb + (size_t)r * DIM;
  float s = 0.f;
  for (int d = 0; d < DIM; d += 4) {
    float4 v = *(const float4*)(row + d);
    s += v.x * v.x + v.y * v.y + v.z * v.z + v.w * v.w;
  }
  cnorm[r] = s;
}

// Build f16 codebook chunk images, PER-WAVE sub-chunks:
//   chunk n=(q,ks): 8 sub-chunks of 4 KB, one per wave w (codes w*128..+127)
//   sub-chunk layout [g:2][c:128][j:8 f16]; element = cb[q][w*128+c][ks*16+g*8+j]
// Linear byte address = n*32768 + w*4096 + g*2048 + c*16 + j*2.
__global__ void k_prep(const float* __restrict__ cb, unsigned char* __restrict__ cbH) {
  unsigned u = blockIdx.x * blockDim.x + threadIdx.x;   // 0..1048575 (8B units)
  unsigned h  = u & 1;                 // j-half (4 f16)
  unsigned v  = u >> 1;                // 16B granule
  unsigned c  = v & 127;
  unsigned g  = (v >> 7) & 1;
  unsigned w  = (v >> 8) & 7;
  unsigned ks = (v >> 11) & 31;
  unsigned q  = v >> 16;
  unsigned code = (w << 7) | c;
  unsigned k = ks * 16 + g * 8 + h * 4;
  float4 val = *(const float4*)(cb + ((size_t)((q << 10) | code)) * DIM + k);
  f16x4 o;
  o[0] = (_Float16)val.x; o[1] = (_Float16)val.y;
  o[2] = (_Float16)val.z; o[3] = (_Float16)val.w;
  *(f16x4*)(cbH + (size_t)u * 8) = o;
}

// stage this wave's 4 KB sub-chunk of global chunk n into a private LDS slot
// (4x global_load_lds dwordx4 per lane; vmcnt += 4, per-wave exact)
__device__ __forceinline__ void stage(const unsigned char* __restrict__ cbH, int n,
                                      unsigned char* slot, int w, int cl) {
  const unsigned char* src = cbH + (size_t)n * CHUNK_BYTES + (w << 12) + (cl << 4);
  #pragma unroll
  for (int i = 0; i < 4; ++i)
    __builtin_amdgcn_global_load_lds(
        (const __attribute__((address_space(1))) void*)(src + i * 1024),
        (__attribute__((address_space(3))) void*)(slot + i * 1024), 16, 0, 0);
}

__launch_bounds__(NTHR, 2)
__global__ void k_main(const float* __restrict__ x, const float* __restrict__ cb,
                       const unsigned char* __restrict__ cbH,
                       const float* __restrict__ cnorm,
                       double* __restrict__ lossAcc,
                       float* __restrict__ out)
{
  // A-plane: f16 resid, row m (64) x 512 k; 16B slot s=k/8 stored at
  // slot' = swap3(s) ^ (m&31) -> conflict-free-ish b128 reads and writes.
  __shared__ __align__(16) unsigned char Af[MPTS * DIM * 2];    // 64 KB
  __shared__ __align__(16) unsigned char Bs[8][2][4096];        // 64 KB, wave-private
  __shared__ float          s1w[MPTS][8];
  __shared__ unsigned short id1w[MPTS][8];
  __shared__ unsigned short cand[MPTS][8][4];
  __shared__ unsigned char  ccnt[MPTS][8];
  __shared__ float          gmA[MPTS];
  __shared__ int            win0A[MPTS];
  __shared__ unsigned short idxs[MPTS][NUMQ];
  __shared__ double         lred[8];

  const int tid = threadIdx.x;
  const int cl  = tid & 63;
  const int w   = tid >> 6;          // wave 0..7; owns codes w*128..+127
  const int l31 = cl & 31;
  const int l5  = cl >> 5;           // k-group within wave
  const int wg  = blockIdx.x;

  // residual registers: thread owns point rp = tid>>3, dims rj*64 .. +64
  const int rp = tid >> 3;
  const int rj = tid & 7;
  const size_t gp = (size_t)wg * MPTS + rp;
  float4 r4[16];
  {
    const float4* xr = (const float4*)(x + gp * DIM + rj * 64);
    #pragma unroll
    for (int i = 0; i < 16; ++i) r4[i] = xr[i];
  }

  unsigned char* mySlot = &Bs[w][0][0];
  const int bOff = l5 * 2048 + l31 * 16;   // B frag byte within slot

  // prologue: prefetch global chunks 0,1 (flight hides under A-build)
  stage(cbH, 0, mySlot, w, cl);
  stage(cbH, 1, mySlot + 4096, w, cl);

  for (int q = 0; q < NUMQ; ++q) {
    // ---- A-plane build: f16(resid), swizzled (verbatim R4)
    #pragma unroll
    for (int i = 0; i < 8; ++i) {
      float4 a = r4[2 * i], b = r4[2 * i + 1];
      f16x8 v;
      v[0] = (_Float16)a.x; v[1] = (_Float16)a.y; v[2] = (_Float16)a.z; v[3] = (_Float16)a.w;
      v[4] = (_Float16)b.x; v[5] = (_Float16)b.y; v[6] = (_Float16)b.z; v[7] = (_Float16)b.w;
      int sl = ((i << 3) | rj) ^ (rp & 31);            // swap3(j*8+i) ^ row
      *(f16x8*)(Af + rp * 1024 + (sl << 4)) = v;
    }
    __syncthreads();

    f32x16 acc[2][4];
    #pragma unroll
    for (int mt = 0; mt < 2; ++mt)
      #pragma unroll
      for (int nt = 0; nt < 4; ++nt)
        #pragma unroll
        for (int e = 0; e < 16; ++e) acc[mt][nt][e] = 0.0f;

    // ---- MFMA K-loop: NO barriers; per-wave exact counted vmcnt;
    //      wave-private double-buffered slots; cross-q staging.
    #pragma unroll 1
    for (int ks = 0; ks < NCHUNK; ++ks) {
      if (q == NUMQ - 1 && ks == NCHUNK - 1)
        asm volatile("s_waitcnt vmcnt(0)" ::: "memory");
      else
        asm volatile("s_waitcnt vmcnt(4)" ::: "memory");   // own chunk ks landed
      const unsigned char* bufp = mySlot + ((ks & 1) << 12);
      const int s5 = (ks << 1) | l5;
      const int sf = ((((s5 & 7) << 3) | (s5 >> 3)) ^ l31) << 4;
      f16x8 a0 = *(const f16x8*)(Af + l31 * 1024 + sf);
      f16x8 a1 = *(const f16x8*)(Af + 32768 + l31 * 1024 + sf);
      f16x8 b0 = *(const f16x8*)(bufp + bOff);
      f16x8 b1 = *(const f16x8*)(bufp + bOff + 512);
      f16x8 b2 = *(const f16x8*)(bufp + bOff + 1024);
      f16x8 b3 = *(const f16x8*)(bufp + bOff + 1536);
      __builtin_amdgcn_s_setprio(1);
      acc[0][0] = __builtin_amdgcn_mfma_f32_32x32x16_f16(a0, b0, acc[0][0], 0, 0, 0);
      acc[0][1] = __builtin_amdgcn_mfma_f32_32x32x16_f16(a0, b1, acc[0][1], 0, 0, 0);
      acc[0][2] = __builtin_amdgcn_mfma_f32_32x32x16_f16(a0, b2, acc[0][2], 0, 0, 0);
      acc[0][3] = __builtin_amdgcn_mfma_f32_32x32x16_f16(a0, b3, acc[0][3], 0, 0, 0);
      acc[1][0] = __builtin_amdgcn_mfma_f32_32x32x16_f16(a1, b0, acc[1][0], 0, 0, 0);
      acc[1][1] = __builtin_amdgcn_mfma_f32_32x32x16_f16(a1, b1, acc[1][1], 0, 0, 0);
      acc[1][2] = __builtin_amdgcn_mfma_f32_32x32x16_f16(a1, b2, acc[1][2], 0, 0, 0);
      acc[1][3] = __builtin_amdgcn_mfma_f32_32x32x16_f16(a1, b3, acc[1][3], 0, 0, 0);
      __builtin_amdgcn_s_setprio(0);
      // own-wave reads of this slot are done before we overwrite it:
      asm volatile("s_waitcnt lgkmcnt(0)" ::: "memory");
      const int n = (q << 5) + ks + 2;                 // global chunk index
      if (n < NCHUNK_TOT) stage(cbH, n, mySlot + ((ks & 1) << 12), w, cl);
    }

    // ---- scores = -2*dot + ||c||^2 (approximate; f16-rounded inputs)
    {
      const float* cnq = cnorm + (q << 10) + (w << 7) + l31;
      const float cn0 = cnq[0], cn1 = cnq[32], cn2 = cnq[64], cn3 = cnq[96];
      #pragma unroll
      for (int mt = 0; mt < 2; ++mt) {
        acc[mt][0] = acc[mt][0] * -2.0f + cn0;
        acc[mt][1] = acc[mt][1] * -2.0f + cn1;
        acc[mt][2] = acc[mt][2] * -2.0f + cn2;
        acc[mt][3] = acc[mt][3] * -2.0f + cn3;
      }
    }

    // ---- pass 1: per-wave per-point top-1 (over this wave's 128 codes)
    // C/D layout 32x32: col = lane&31, row = (r&3)+8*(r>>2)+4*(lane>>5)
    #pragma unroll
    for (int mt = 0; mt < 2; ++mt)
      #pragma unroll
      for (int r = 0; r < 16; ++r) {
        float s = acc[mt][0][r]; int bi = l31;
        if (acc[mt][1][r] < s) { s = acc[mt][1][r]; bi = 32 + l31; }
        if (acc[mt][2][r] < s) { s = acc[mt][2][r]; bi = 64 + l31; }
        if (acc[mt][3][r] < s) { s = acc[mt][3][r]; bi = 96 + l31; }
        #pragma unroll
        for (int m = 1; m < 32; m <<= 1) {
          float os = __shfl_xor(s, m); int ob = __shfl_xor(bi, m);
          if (os < s || (os == s && ob < bi)) { s = os; bi = ob; }
        }
        if (l31 == 0) {
          int p = mt * 32 + (r & 3) + 8 * (r >> 2) + 4 * l5;
          s1w[p][w] = s; id1w[p][w] = (unsigned short)bi;
        }
      }
    __syncthreads();

    // ---- pass 2: global min + provisional winner per point
    if (tid < MPTS) {
      int p = tid;
      float bs = s1w[p][0]; int bi = id1w[p][0];
      #pragma unroll
      for (int ww = 1; ww < 8; ++ww) {
        float s = s1w[p][ww];
        if (s < bs) { bs = s; bi = ww * 128 + id1w[p][ww]; }
      }
      gmA[p] = bs; win0A[p] = bi;
    }
    __syncthreads();

    // ---- pass 3: ballot candidates within margin of global min
    //      (margin 1.5 vs f16 score error sigma~0.03; proven R4)
    #pragma unroll
    for (int mt = 0; mt < 2; ++mt)
      #pragma unroll
      for (int r = 0; r < 16; ++r) {
        const int p0 = mt * 32 + (r & 3) + 8 * (r >> 2);
        const float g0 = gmA[p0], g1 = gmA[p0 + 4];
        const float lim0 = g0 + 1.5f + 1e-4f * fabsf(g0);
        const float lim1 = g1 + 1.5f + 1e-4f * fabsf(g1);
        const float lim = l5 ? lim1 : lim0;
        unsigned long long b0 = __ballot(acc[mt][0][r] <= lim);
        unsigned long long b1 = __ballot(acc[mt][1][r] <= lim);
        unsigned long long b2 = __ballot(acc[mt][2][r] <= lim);
        unsigned long long b3 = __ballot(acc[mt][3][r] <= lim);
        if (cl == 0 || cl == 32) {
          const int p = p0 + (cl >> 3);
          unsigned short* cd = &cand[p][w][0];
          unsigned m0 = (cl == 0) ? (unsigned)b0 : (unsigned)(b0 >> 32);
          unsigned m1 = (cl == 0) ? (unsigned)b1 : (unsigned)(b1 >> 32);
          unsigned m2 = (cl == 0) ? (unsigned)b2 : (unsigned)(b2 >> 32);
          unsigned m3 = (cl == 0) ? (unsigned)b3 : (unsigned)(b3 >> 32);
          int n = 0;
          while (m0 && n < 4) { int bt = __builtin_ctz(m0); m0 &= m0 - 1; cd[n++] = (unsigned short)(bt); }
          while (m1 && n < 4) { int bt = __builtin_ctz(m1); m1 &= m1 - 1; cd[n++] = (unsigned short)(32 + bt); }
          while (m2 && n < 4) { int bt = __builtin_ctz(m2); m2 &= m2 - 1; cd[n++] = (unsigned short)(64 + bt); }
          while (m3 && n < 4) { int bt = __builtin_ctz(m3); m3 &= m3 - 1; cd[n++] = (unsigned short)(96 + bt); }
          ccnt[p][w] = (unsigned char)n;
        }
      }
    __syncthreads();

    // ---- pass 4: refinement tiers (wave w owns points w*8..w*8+7; their
    //      fp32 residual lives in this wave's r4 registers, 8 lanes/point)
    #pragma unroll 1
    for (int pp = 0; pp < 8; ++pp) {
      const int p = (w << 3) + pp;
      int tot = 0;
      #pragma unroll
      for (int ww = 0; ww < 8; ++ww) tot += ccnt[p][ww];
      int winner;
      if (tot <= 1) {
        winner = win0A[p];
      } else {
        const size_t gpp = (size_t)wg * MPTS + p;
        // tier 1: fp64 dot vs exact fp32 residual (in regs)
        double bs = 1.0e300, bs2 = 1.0e300; int bi = 0x7FFFFFFF;
        #pragma unroll 1
        for (int ww = 0; ww < 8; ++ww) {
          const int nn = ccnt[p][ww];
          #pragma unroll 1
          for (int si = 0; si < nn; ++si) {
            const int cc = ww * 128 + cand[p][ww][si];
            const float4* cr = (const float4*)(cb + ((size_t)q * CODES + cc) * DIM + (cl & 7) * 64);
            double dt = 0.0, cs = 0.0;
            #pragma unroll
            for (int i = 0; i < 16; ++i) {
              float4 cv = cr[i];
              dt += (double)r4[i].x * cv.x + (double)r4[i].y * cv.y
                  + (double)r4[i].z * cv.z + (double)r4[i].w * cv.w;
              cs += (double)cv.x * cv.x + (double)cv.y * cv.y
                  + (double)cv.z * cv.z + (double)cv.w * cv.w;
            }
            #pragma unroll
            for (int m = 1; m < 8; m <<= 1) { dt += __shfl_xor(dt, m); cs += __shfl_xor(cs, m); }
            double dtb = __shfl(dt, pp * 8), csb = __shfl(cs, pp * 8);
            double s = -2.0 * dtb + csb;
            if (s < bs) { bs2 = bs; bs = s; bi = cc; }
            else if (s < bs2) { bs2 = s; }
          }
        }
        // tier 2: exact fp64 chain rebuild from x (rare: <1e-3 gap)
        if (bs2 - bs <= 1e-3 + 1e-6 * fabs(bs)) {
          bs = 1.0e300; bi = 0x7FFFFFFF;
          const float4* xr2 = (const float4*)(x + gpp * DIM + (cl & 7) * 64);
          #pragma unroll 1
          for (int ww = 0; ww < 8; ++ww) {
            const int nn = ccnt[p][ww];
            #pragma unroll 1
            for (int si = 0; si < nn; ++si) {
              const int cc = ww * 128 + cand[p][ww][si];
              const float4* cr = (const float4*)(cb + ((size_t)q * CODES + cc) * DIM + (cl & 7) * 64);
              double dt = 0.0, cs = 0.0;
              #pragma unroll 1
              for (int i = 0; i < 16; ++i) {
                float4 xv = xr2[i];
                double rhx = xv.x, rhy = xv.y, rhz = xv.z, rhw = xv.w;
                #pragma unroll 1
                for (int t2 = 0; t2 < q; ++t2) {
                  const float4* qr = (const float4*)(cb + ((size_t)t2 * CODES + idxs[p][t2]) * DIM + (cl & 7) * 64);
                  float4 qv = qr[i];
                  rhx -= (double)qv.x; rhy -= (double)qv.y;
                  rhz -= (double)qv.z; rhw -= (double)qv.w;
                }
                float4 cv = cr[i];
                dt += rhx * cv.x + rhy * cv.y + rhz * cv.z + rhw * cv.w;
                cs += (double)cv.x * cv.x + (double)cv.y * cv.y
                    + (double)cv.z * cv.z + (double)cv.w * cv.w;
              }
              #pragma unroll
              for (int m = 1; m < 8; m <<= 1) { dt += __shfl_xor(dt, m); cs += __shfl_xor(cs, m); }
              double dtb = __shfl(dt, pp * 8), csb = __shfl(cs, pp * 8);
              double s = -2.0 * dtb + csb;
              if (s < bs || (s == bs && cc < bi)) { bs = s; bi = cc; }
            }
          }
        }
        winner = bi;
      }
      if (cl == 0) idxs[p][q] = (unsigned short)winner;
    }
    __syncthreads();

    // ---- pass 5: residual update (exact fp32 chain) + commit loss (fp64)
    {
      const int win = idxs[rp][q];
      const float4* cr = (const float4*)(cb + ((size_t)q * CODES + win) * DIM + rj * 64);
      double ls = 0.0;
      #pragma unroll
      for (int i = 0; i < 16; ++i) {
        float4 cv = cr[i];
        float dx = cv.x - r4[i].x, dy = cv.y - r4[i].y;
        float dz = cv.z - r4[i].z, dw = cv.w - r4[i].w;
        ls += (double)dx * dx + (double)dy * dy + (double)dz * dz + (double)dw * dw;
        r4[i].x -= cv.x; r4[i].y -= cv.y; r4[i].z -= cv.z; r4[i].w -= cv.w;
      }
      #pragma unroll
      for (int m = 1; m < 64; m <<= 1) ls += __shfl_xor(ls, m);
      if (cl == 0) lred[w] = ls;
      __syncthreads();
      if (tid == 0) {
        double t = lred[0] + lred[1] + lred[2] + lred[3]
                 + lred[4] + lred[5] + lred[6] + lred[7];
        atomicAdd(lossAcc + q, t);
      }
      __syncthreads();
    }
  } // q

  // ---- outputs: quantized = x - resid_final; indices as float
  {
    const float4* xr = (const float4*)(x + gp * DIM + rj * 64);
    float4* orow = (float4*)(out + gp * DIM + rj * 64);
    #pragma unroll
    for (int i = 0; i < 16; ++i) {
      float4 xv = xr[i];
      float4 o;
      o.x = xv.x - r4[i].x; o.y = xv.y - r4[i].y;
      o.z = xv.z - r4[i].z; o.w = xv.w - r4[i].w;
      orow[i] = o;
    }
  }
  if (tid < MPTS) {
    float* ob = out + OUT_IDX + ((size_t)wg * MPTS + tid) * NUMQ;
    #pragma unroll
    for (int j = 0; j < NUMQ; ++j) ob[j] = (float)idxs[tid][j];
  }
}

__global__ void k_fin(const double* __restrict__ loss, float* __restrict__ out) {
  int t = threadIdx.x;
  if (t < NUMQ)
    out[OUT_LOSS + t] = (float)(loss[t] / (double)((size_t)BATCH * SEQ * DIM));
}

extern "C" void kernel_launch(void* const* d_in, const int* in_sizes, int n_in,
                              void* d_out, int out_size, void* d_ws, size_t ws_size,
                              hipStream_t stream) {
  (void)in_sizes; (void)n_in; (void)out_size; (void)ws_size;
  const float* x  = (const float*)d_in[0];
  const float* cb = (const float*)d_in[1];
  float* out = (float*)d_out;
  char* ws = (char*)d_ws;
  double* loss = (double*)(ws + WS_LOSS);
  float* cnorm = (float*)(ws + WS_CNORM);
  unsigned char* cbH = (unsigned char*)(ws + WS_CBH);   // 8.39 MB

  k_zero<<<1, 64, 0, stream>>>(loss);
  k_cnorm<<<NUMQ * CODES / 256, 256, 0, stream>>>(cb, cnorm);
  k_prep<<<NUMQ * NCHUNK * CHUNK_BYTES / 8 / 256, 256, 0, stream>>>(cb, cbH);
  k_main<<<NWG, NTHR, 0, stream>>>(x, cb, cbH, cnorm, loss, out);
  k_fin<<<1, 64, 0, stream>>>(loss, out);
}

// Round 4
// 628.362 us; speedup vs baseline: 1.1594x; 1.0059x over previous
//
#include <hip/hip_runtime.h>
#include <cstdint>
#include <cstddef>

// ---------------------------------------------------------------------------
// Residual VQ (SoundStream Alg.1) on MI355X — R7: 2 blocks/CU.
// R6 post-mortem: barrier-free K-loop gained only 10 us (582->572) with
// identical counters -> stalls are NOT cross-wave lockstep; kernel is
// latency-bound with 2 waves/SIMD (256 regs/wave: acc 128 + r4 64) and
// pipe-busy sum ~235 us vs 572 us wall. Block quantization (8-wave blocks,
// 2048-reg SIMD file) means the only next occupancy step is 16 waves/CU =
// 2 blocks x <=128 regs/wave.
// R7: MPTS=32 (acc[4]=64 regs, r4=32 regs, ~121 peak), LDS 69 KB
// (Af 32 KB + single-buffer wave-private Bs 32 KB + extras) -> 2 blocks/CU,
// 4 waves/SIMD. Single-buffer staging exposes ~250cy L2 latency per K-step
// per wave; 4 waves x ~130cy compute/iter covers it (TLP replaces the
// double-buffer we no longer have LDS for). Barrier-free K-loop + cross-q
// prefetch retained from R6. Epilogue partition = 16 thr/pt, 4 pts/wave
// (R5's proven layout); margins/tiers/numerics verbatim -> indices exact.
// ---------------------------------------------------------------------------

#define BATCH 8
#define SEQ   2048
#define DIM   512
#define NUMQ  8
#define CODES 1024
#define NPTS  (BATCH*SEQ)            // 16384
#define MPTS  32                     // points per workgroup
#define NWG   (NPTS/MPTS)            // 512 = 2 WGs per CU
#define NTHR  512                    // 8 waves
#define NCHUNK 32                    // K-steps of 16 per quantizer
#define NCHUNK_TOT (NUMQ*NCHUNK)     // 256 global chunks
#define CHUNK_BYTES 32768            // per global chunk: [w:8][g:2][c:128][j:8 f16]

#define OUT_IDX   (BATCH*SEQ*DIM)             // 8388608
#define OUT_LOSS  (OUT_IDX + BATCH*SEQ*NUMQ)  // 8519680

#define WS_LOSS   0                           // 8 doubles
#define WS_CNORM  1024                        // 8192 floats
#define WS_CBH    40960                       // f16 chunk images, 8.39 MB

typedef _Float16 f16x8  __attribute__((ext_vector_type(8)));
typedef _Float16 f16x4  __attribute__((ext_vector_type(4)));
typedef float    f32x16 __attribute__((ext_vector_type(16)));

__global__ void k_zero(double* loss) {
  if (threadIdx.x < NUMQ) loss[threadIdx.x] = 0.0;
}

// per-code squared norm (fp32; only feeds the approximate scores)
__global__ void k_cnorm(const float* __restrict__ cb, float* __restrict__ cnorm) {
  int r = blockIdx.x * blockDim.x + threadIdx.x;      // 0..8191
  const float* row = cb + (size_t)r * DIM;
  float s = 0.f;
  for (int d = 0; d < DIM; d += 4) {
    float4 v = *(const float4*)(row + d);
    s += v.x * v.x + v.y * v.y + v.z * v.z + v.w * v.w;
  }
  cnorm[r] = s;
}

// Build f16 codebook chunk images, PER-WAVE sub-chunks (verbatim R6):
//   chunk n=(q,ks): 8 sub-chunks of 4 KB, one per wave w (codes w*128..+127)
//   sub-chunk layout [g:2][c:128][j:8 f16]; element = cb[q][w*128+c][ks*16+g*8+j]
__global__ void k_prep(const float* __restrict__ cb, unsigned char* __restrict__ cbH) {
  unsigned u = blockIdx.x * blockDim.x + threadIdx.x;   // 0..1048575 (8B units)
  unsigned h  = u & 1;                 // j-half (4 f16)
  unsigned v  = u >> 1;                // 16B granule
  unsigned c  = v & 127;
  unsigned g  = (v >> 7) & 1;
  unsigned w  = (v >> 8) & 7;
  unsigned ks = (v >> 11) & 31;
  unsigned q  = v >> 16;
  unsigned code = (w << 7) | c;
  unsigned k = ks * 16 + g * 8 + h * 4;
  float4 val = *(const float4*)(cb + ((size_t)((q << 10) | code)) * DIM + k);
  f16x4 o;
  o[0] = (_Float16)val.x; o[1] = (_Float16)val.y;
  o[2] = (_Float16)val.z; o[3] = (_Float16)val.w;
  *(f16x4*)(cbH + (size_t)u * 8) = o;
}

// stage this wave's 4 KB sub-chunk of global chunk n into its private slot
// (4x global_load_lds dwordx4 per lane; vmcnt += 4, per-wave exact)
__device__ __forceinline__ void stage(const unsigned char* __restrict__ cbH, int n,
                                      unsigned char* slot, int w, int cl) {
  const unsigned char* src = cbH + (size_t)n * CHUNK_BYTES + (w << 12) + (cl << 4);
  #pragma unroll
  for (int i = 0; i < 4; ++i)
    __builtin_amdgcn_global_load_lds(
        (const __attribute__((address_space(1))) void*)(src + i * 1024),
        (__attribute__((address_space(3))) void*)(slot + i * 1024), 16, 0, 0);
}

__launch_bounds__(NTHR, 4)
__global__ void k_main(const float* __restrict__ x, const float* __restrict__ cb,
                       const unsigned char* __restrict__ cbH,
                       const float* __restrict__ cnorm,
                       double* __restrict__ lossAcc,
                       float* __restrict__ out)
{
  // A-plane: f16 resid, row m (32) x 512 k; 16B slot s=k/8 stored at
  // slot' = swap3(s) ^ (m&31) -> spread b128 reads/writes across banks.
  __shared__ __align__(16) unsigned char Af[MPTS * DIM * 2];    // 32 KB
  __shared__ __align__(16) unsigned char Bs[8][4096];           // 32 KB, wave-private
  __shared__ float          s1w[MPTS][8];
  __shared__ unsigned short id1w[MPTS][8];
  __shared__ unsigned short cand[MPTS][8][4];
  __shared__ unsigned char  ccnt[MPTS][8];
  __shared__ float          gmA[MPTS];
  __shared__ int            win0A[MPTS];
  __shared__ unsigned short idxs[MPTS][NUMQ];
  __shared__ double         lred[8];

  const int tid = threadIdx.x;
  const int cl  = tid & 63;
  const int w   = tid >> 6;          // wave 0..7; owns codes w*128..+127
  const int l31 = cl & 31;
  const int l5  = cl >> 5;           // k-group within wave
  const int wg  = blockIdx.x;

  // residual registers: thread owns point rp = tid>>4, dims rj*32 .. +32
  const int rp = tid >> 4;
  const int rj = tid & 15;
  const size_t gp = (size_t)wg * MPTS + rp;
  float4 r4[8];
  {
    const float4* xr = (const float4*)(x + gp * DIM + rj * 32);
    #pragma unroll
    for (int i = 0; i < 8; ++i) r4[i] = xr[i];
  }

  unsigned char* mySlot = &Bs[w][0];
  const int bOff = l5 * 2048 + l31 * 16;   // B frag byte within slot

  // prologue: prefetch chunk 0 (flight hides under A-build + barrier drain)
  stage(cbH, 0, mySlot, w, cl);

  for (int q = 0; q < NUMQ; ++q) {
    // ---- A-plane build: f16(resid), swizzled
    #pragma unroll
    for (int i = 0; i < 4; ++i) {
      float4 a = r4[2 * i], b = r4[2 * i + 1];
      f16x8 v;
      v[0] = (_Float16)a.x; v[1] = (_Float16)a.y; v[2] = (_Float16)a.z; v[3] = (_Float16)a.w;
      v[4] = (_Float16)b.x; v[5] = (_Float16)b.y; v[6] = (_Float16)b.z; v[7] = (_Float16)b.w;
      const int s = rj * 4 + i;                        // logical slot = k/8
      const int sl = (((s & 7) << 3) | (s >> 3)) ^ (rp & 31);
      *(f16x8*)(Af + rp * 1024 + (sl << 4)) = v;
    }
    __syncthreads();   // also drains vmcnt -> prefetched chunk landed

    f32x16 acc[4];
    #pragma unroll
    for (int nt = 0; nt < 4; ++nt)
      #pragma unroll
      for (int e = 0; e < 16; ++e) acc[nt][e] = 0.0f;

    // ---- MFMA K-loop: no barriers; single wave-private slot; prefetch
    //      of chunk ks+1 issued after this chunk's LDS reads complete.
    #pragma unroll 1
    for (int ks = 0; ks < NCHUNK; ++ks) {
      asm volatile("s_waitcnt vmcnt(0)" ::: "memory");   // chunk ks landed
      const int s5 = (ks << 1) | l5;
      const int sf = ((((s5 & 7) << 3) | (s5 >> 3)) ^ l31) << 4;
      f16x8 a0 = *(const f16x8*)(Af + l31 * 1024 + sf);
      f16x8 b0 = *(const f16x8*)(mySlot + bOff);
      f16x8 b1 = *(const f16x8*)(mySlot + bOff + 512);
      f16x8 b2 = *(const f16x8*)(mySlot + bOff + 1024);
      f16x8 b3 = *(const f16x8*)(mySlot + bOff + 1536);
      __builtin_amdgcn_s_setprio(1);
      acc[0] = __builtin_amdgcn_mfma_f32_32x32x16_f16(a0, b0, acc[0], 0, 0, 0);
      acc[1] = __builtin_amdgcn_mfma_f32_32x32x16_f16(a0, b1, acc[1], 0, 0, 0);
      acc[2] = __builtin_amdgcn_mfma_f32_32x32x16_f16(a0, b2, acc[2], 0, 0, 0);
      acc[3] = __builtin_amdgcn_mfma_f32_32x32x16_f16(a0, b3, acc[3], 0, 0, 0);
      __builtin_amdgcn_s_setprio(0);
      // own-wave LDS reads done (MFMA operands in regs) -> safe to overwrite
      asm volatile("s_waitcnt lgkmcnt(0)" ::: "memory");
      const int n = (q << 5) + ks + 1;                 // next global chunk
      if (n < NCHUNK_TOT) stage(cbH, n, mySlot, w, cl);
    }

    // ---- scores = -2*dot + ||c||^2 (approximate; f16-rounded inputs)
    {
      const float* cnq = cnorm + (q << 10) + (w << 7) + l31;
      const float cn0 = cnq[0], cn1 = cnq[32], cn2 = cnq[64], cn3 = cnq[96];
      acc[0] = acc[0] * -2.0f + cn0;
      acc[1] = acc[1] * -2.0f + cn1;
      acc[2] = acc[2] * -2.0f + cn2;
      acc[3] = acc[3] * -2.0f + cn3;
    }

    // ---- pass 1: per-wave per-point top-1 (over this wave's 128 codes)
    // C/D layout 32x32: col = lane&31, row = (r&3)+8*(r>>2)+4*(lane>>5)
    #pragma unroll
    for (int r = 0; r < 16; ++r) {
      float s = acc[0][r]; int bi = l31;
      if (acc[1][r] < s) { s = acc[1][r]; bi = 32 + l31; }
      if (acc[2][r] < s) { s = acc[2][r]; bi = 64 + l31; }
      if (acc[3][r] < s) { s = acc[3][r]; bi = 96 + l31; }
      #pragma unroll
      for (int m = 1; m < 32; m <<= 1) {
        float os = __shfl_xor(s, m); int ob = __shfl_xor(bi, m);
        if (os < s || (os == s && ob < bi)) { s = os; bi = ob; }
      }
      if (l31 == 0) {
        int p = (r & 3) + 8 * (r >> 2) + 4 * l5;
        s1w[p][w] = s; id1w[p][w] = (unsigned short)bi;
      }
    }
    __syncthreads();

    // ---- pass 2: global min + provisional winner per point
    if (tid < MPTS) {
      int p = tid;
      float bs = s1w[p][0]; int bi = id1w[p][0];
      #pragma unroll
      for (int ww = 1; ww < 8; ++ww) {
        float s = s1w[p][ww];
        if (s < bs) { bs = s; bi = ww * 128 + id1w[p][ww]; }
      }
      gmA[p] = bs; win0A[p] = bi;
    }
    __syncthreads();

    // ---- pass 3: ballot candidates within margin of global min
    //      (margin 1.5 vs f16 score error sigma~0.03; proven R4/R6)
    #pragma unroll
    for (int r = 0; r < 16; ++r) {
      const int p0 = (r & 3) + 8 * (r >> 2);
      const float g0 = gmA[p0], g1 = gmA[p0 + 4];
      const float lim0 = g0 + 1.5f + 1e-4f * fabsf(g0);
      const float lim1 = g1 + 1.5f + 1e-4f * fabsf(g1);
      const float lim = l5 ? lim1 : lim0;
      unsigned long long b0 = __ballot(acc[0][r] <= lim);
      unsigned long long b1 = __ballot(acc[1][r] <= lim);
      unsigned long long b2 = __ballot(acc[2][r] <= lim);
      unsigned long long b3 = __ballot(acc[3][r] <= lim);
      if (cl == 0 || cl == 32) {
        const int p = p0 + (cl >> 3);                  // cl=32 -> p0+4
        unsigned short* cd = &cand[p][w][0];
        unsigned m0 = (cl == 0) ? (unsigned)b0 : (unsigned)(b0 >> 32);
        unsigned m1 = (cl == 0) ? (unsigned)b1 : (unsigned)(b1 >> 32);
        unsigned m2 = (cl == 0) ? (unsigned)b2 : (unsigned)(b2 >> 32);
        unsigned m3 = (cl == 0) ? (unsigned)b3 : (unsigned)(b3 >> 32);
        int n = 0;
        while (m0 && n < 4) { int bt = __builtin_ctz(m0); m0 &= m0 - 1; cd[n++] = (unsigned short)(bt); }
        while (m1 && n < 4) { int bt = __builtin_ctz(m1); m1 &= m1 - 1; cd[n++] = (unsigned short)(32 + bt); }
        while (m2 && n < 4) { int bt = __builtin_ctz(m2); m2 &= m2 - 1; cd[n++] = (unsigned short)(64 + bt); }
        while (m3 && n < 4) { int bt = __builtin_ctz(m3); m3 &= m3 - 1; cd[n++] = (unsigned short)(96 + bt); }
        ccnt[p][w] = (unsigned char)n;
      }
    }
    __syncthreads();

    // ---- pass 4: refinement tiers (wave w owns points w*4..w*4+3; their
    //      fp32 residual lives in this wave's r4 registers, 16 lanes/point)
    #pragma unroll 1
    for (int pp = 0; pp < 4; ++pp) {
      const int p = (w << 2) + pp;
      int tot = 0;
      #pragma unroll
      for (int ww = 0; ww < 8; ++ww) tot += ccnt[p][ww];
      int winner;
      if (tot <= 1) {
        winner = win0A[p];
      } else {
        const size_t gpp = (size_t)wg * MPTS + p;
        // tier 1: fp64 dot vs exact fp32 residual (in regs)
        double bs = 1.0e300, bs2 = 1.0e300; int bi = 0x7FFFFFFF;
        #pragma unroll 1
        for (int ww = 0; ww < 8; ++ww) {
          const int nn = ccnt[p][ww];
          #pragma unroll 1
          for (int si = 0; si < nn; ++si) {
            const int cc = ww * 128 + cand[p][ww][si];
            const float4* cr = (const float4*)(cb + ((size_t)q * CODES + cc) * DIM + (cl & 15) * 32);
            double dt = 0.0, cs = 0.0;
            #pragma unroll
            for (int i = 0; i < 8; ++i) {
              float4 cv = cr[i];
              dt += (double)r4[i].x * cv.x + (double)r4[i].y * cv.y
                  + (double)r4[i].z * cv.z + (double)r4[i].w * cv.w;
              cs += (double)cv.x * cv.x + (double)cv.y * cv.y
                  + (double)cv.z * cv.z + (double)cv.w * cv.w;
            }
            #pragma unroll
            for (int m = 1; m < 16; m <<= 1) { dt += __shfl_xor(dt, m); cs += __shfl_xor(cs, m); }
            double dtb = __shfl(dt, pp * 16), csb = __shfl(cs, pp * 16);
            double s = -2.0 * dtb + csb;
            if (s < bs) { bs2 = bs; bs = s; bi = cc; }
            else if (s < bs2) { bs2 = s; }
          }
        }
        // tier 2: exact fp64 chain rebuild from x (rare: <1e-3 gap)
        if (bs2 - bs <= 1e-3 + 1e-6 * fabs(bs)) {
          bs = 1.0e300; bi = 0x7FFFFFFF;
          const float4* xr2 = (const float4*)(x + gpp * DIM + (cl & 15) * 32);
          #pragma unroll 1
          for (int ww = 0; ww < 8; ++ww) {
            const int nn = ccnt[p][ww];
            #pragma unroll 1
            for (int si = 0; si < nn; ++si) {
              const int cc = ww * 128 + cand[p][ww][si];
              const float4* cr = (const float4*)(cb + ((size_t)q * CODES + cc) * DIM + (cl & 15) * 32);
              double dt = 0.0, cs = 0.0;
              #pragma unroll 1
              for (int i = 0; i < 8; ++i) {
                float4 xv = xr2[i];
                double rhx = xv.x, rhy = xv.y, rhz = xv.z, rhw = xv.w;
                #pragma unroll 1
                for (int t2 = 0; t2 < q; ++t2) {
                  const float4* qr = (const float4*)(cb + ((size_t)t2 * CODES + idxs[p][t2]) * DIM + (cl & 15) * 32);
                  float4 qv = qr[i];
                  rhx -= (double)qv.x; rhy -= (double)qv.y;
                  rhz -= (double)qv.z; rhw -= (double)qv.w;
                }
                float4 cv = cr[i];
                dt += rhx * cv.x + rhy * cv.y + rhz * cv.z + rhw * cv.w;
                cs += (double)cv.x * cv.x + (double)cv.y * cv.y
                    + (double)cv.z * cv.z + (double)cv.w * cv.w;
              }
              #pragma unroll
              for (int m = 1; m < 16; m <<= 1) { dt += __shfl_xor(dt, m); cs += __shfl_xor(cs, m); }
              double dtb = __shfl(dt, pp * 16), csb = __shfl(cs, pp * 16);
              double s = -2.0 * dtb + csb;
              if (s < bs || (s == bs && cc < bi)) { bs = s; bi = cc; }
            }
          }
        }
        winner = bi;
      }
      if (cl == 0) idxs[p][q] = (unsigned short)winner;
    }
    __syncthreads();

    // ---- pass 5: residual update (exact fp32 chain) + commit loss (fp64)
    {
      const int win = idxs[rp][q];
      const float4* cr = (const float4*)(cb + ((size_t)q * CODES + win) * DIM + rj * 32);
      double ls = 0.0;
      #pragma unroll
      for (int i = 0; i < 8; ++i) {
        float4 cv = cr[i];
        float dx = cv.x - r4[i].x, dy = cv.y - r4[i].y;
        float dz = cv.z - r4[i].z, dw = cv.w - r4[i].w;
        ls += (double)dx * dx + (double)dy * dy + (double)dz * dz + (double)dw * dw;
        r4[i].x -= cv.x; r4[i].y -= cv.y; r4[i].z -= cv.z; r4[i].w -= cv.w;
      }
      #pragma unroll
      for (int m = 1; m < 64; m <<= 1) ls += __shfl_xor(ls, m);
      if (cl == 0) lred[w] = ls;
      __syncthreads();
      if (tid == 0) {
        double t = lred[0] + lred[1] + lred[2] + lred[3]
                 + lred[4] + lred[5] + lred[6] + lred[7];
        atomicAdd(lossAcc + q, t);
      }
      __syncthreads();
    }
  } // q

  // ---- outputs: quantized = x - resid_final; indices as float
  {
    const float4* xr = (const float4*)(x + gp * DIM + rj * 32);
    float4* orow = (float4*)(out + gp * DIM + rj * 32);
    #pragma unroll
    for (int i = 0; i < 8; ++i) {
      float4 xv = xr[i];
      float4 o;
      o.x = xv.x - r4[i].x; o.y = xv.y - r4[i].y;
      o.z = xv.z - r4[i].z; o.w = xv.w - r4[i].w;
      orow[i] = o;
    }
  }
  if (tid < MPTS) {
    float* ob = out + OUT_IDX + ((size_t)wg * MPTS + tid) * NUMQ;
    #pragma unroll
    for (int j = 0; j < NUMQ; ++j) ob[j] = (float)idxs[tid][j];
  }
}

__global__ void k_fin(const double* __restrict__ loss, float* __restrict__ out) {
  int t = threadIdx.x;
  if (t < NUMQ)
    out[OUT_LOSS + t] = (float)(loss[t] / (double)((size_t)BATCH * SEQ * DIM));
}

extern "C" void kernel_launch(void* const* d_in, const int* in_sizes, int n_in,
                              void* d_out, int out_size, void* d_ws, size_t ws_size,
                              hipStream_t stream) {
  (void)in_sizes; (void)n_in; (void)out_size; (void)ws_size;
  const float* x  = (const float*)d_in[0];
  const float* cb = (const float*)d_in[1];
  float* out = (float*)d_out;
  char* ws = (char*)d_ws;
  double* loss = (double*)(ws + WS_LOSS);
  float* cnorm = (float*)(ws + WS_CNORM);
  unsigned char* cbH = (unsigned char*)(ws + WS_CBH);   // 8.39 MB

  k_zero<<<1, 64, 0, stream>>>(loss);
  k_cnorm<<<NUMQ * CODES / 256, 256, 0, stream>>>(cb, cnorm);
  k_prep<<<NUMQ * NCHUNK * CHUNK_BYTES / 8 / 256, 256, 0, stream>>>(cb, cbH);
  k_main<<<NWG, NTHR, 0, stream>>>(x, cb, cbH, cnorm, loss, out);
  k_fin<<<1, 64, 0, stream>>>(loss, out);
}

// Round 5
// 613.070 us; speedup vs baseline: 1.1883x; 1.0249x over previous
//
#include <hip/hip_runtime.h>
#include <cstdint>
#include <cstddef>

// ---------------------------------------------------------------------------
// Residual VQ (SoundStream Alg.1) on MI355X — R8: register-staged B.
// R4/R6/R7 invariance (~570 us across barrier removal, occupancy doubling,
// buffer depth changes) exonerates lockstep and occupancy. Common factor:
// the B staging path — 8192 global_load_lds DMAs per CU pulling the 8.4 MB
// chunk image (L2-miss -> L3 latency) with prefetch distance ~300cy << L3
// latency; every K-iter of every wave stalls on vmcnt.
// R8: B-fragments load DIRECTLY into registers (4x dwordx4 per lane per
// chunk, coalesced), 2-slot named register ring software-pipeline (issue
// chunk ks+2 right after ks consumed; compiler emits counted vmcnt(4) —
// G7). No LDS for B at all: no DMA queue, no lgkm coupling, LDS ~75 KB
// (A-plane only). Regs: acc 128 + r4 64 + ring 32 + a 8 ~ 244 @ 2 waves/
// SIMD (launch_bounds(512,2), R6's proven config). A-build, swizzle,
// passes 1-5, margins, exactness tiers verbatim R6 (absmax 0.03125).
// ---------------------------------------------------------------------------

#define BATCH 8
#define SEQ   2048
#define DIM   512
#define NUMQ  8
#define CODES 1024
#define NPTS  (BATCH*SEQ)            // 16384
#define MPTS  64                     // points per workgroup
#define NWG   (NPTS/MPTS)            // 256 = 1 WG per CU
#define NTHR  512                    // 8 waves
#define NCHUNK 32                    // K-steps of 16 per quantizer
#define CHUNK_BYTES 32768            // per global chunk: [w:8][g:2][c:128][j:8 f16]

#define OUT_IDX   (BATCH*SEQ*DIM)             // 8388608
#define OUT_LOSS  (OUT_IDX + BATCH*SEQ*NUMQ)  // 8519680

#define WS_LOSS   0                           // 8 doubles
#define WS_CNORM  1024                        // 8192 floats
#define WS_CBH    40960                       // f16 chunk images, 8.39 MB

typedef _Float16 f16x8  __attribute__((ext_vector_type(8)));
typedef _Float16 f16x4  __attribute__((ext_vector_type(4)));
typedef float    f32x16 __attribute__((ext_vector_type(16)));

__global__ void k_zero(double* loss) {
  if (threadIdx.x < NUMQ) loss[threadIdx.x] = 0.0;
}

// per-code squared norm (fp32; only feeds the approximate scores)
__global__ void k_cnorm(const float* __restrict__ cb, float* __restrict__ cnorm) {
  int r = blockIdx.x * blockDim.x + threadIdx.x;      // 0..8191
  const float* row = cb + (size_t)r * DIM;
  float s = 0.f;
  for (int d = 0; d < DIM; d += 4) {
    float4 v = *(const float4*)(row + d);
    s += v.x * v.x + v.y * v.y + v.z * v.z + v.w * v.w;
  }
  cnorm[r] = s;
}

// Build f16 codebook chunk images, PER-WAVE sub-chunks (verbatim R6):
//   chunk n=(q,ks): 8 sub-chunks of 4 KB, one per wave w (codes w*128..+127)
//   sub-chunk layout [g:2][c:128][j:8 f16]; element = cb[q][w*128+c][ks*16+g*8+j]
__global__ void k_prep(const float* __restrict__ cb, unsigned char* __restrict__ cbH) {
  unsigned u = blockIdx.x * blockDim.x + threadIdx.x;   // 0..1048575 (8B units)
  unsigned h  = u & 1;                 // j-half (4 f16)
  unsigned v  = u >> 1;                // 16B granule
  unsigned c  = v & 127;
  unsigned g  = (v >> 7) & 1;
  unsigned w  = (v >> 8) & 7;
  unsigned ks = (v >> 11) & 31;
  unsigned q  = v >> 16;
  unsigned code = (w << 7) | c;
  unsigned k = ks * 16 + g * 8 + h * 4;
  float4 val = *(const float4*)(cb + ((size_t)((q << 10) | code)) * DIM + k);
  f16x4 o;
  o[0] = (_Float16)val.x; o[1] = (_Float16)val.y;
  o[2] = (_Float16)val.z; o[3] = (_Float16)val.w;
  *(f16x4*)(cbH + (size_t)u * 8) = o;
}

// one chunk's 4 B-fragments for this lane (4x global_load_dwordx4, coalesced)
struct BF { f16x8 b0, b1, b2, b3; };
__device__ __forceinline__ BF loadB(const unsigned char* __restrict__ p) {
  BF r;
  r.b0 = *(const f16x8*)(p);
  r.b1 = *(const f16x8*)(p + 512);
  r.b2 = *(const f16x8*)(p + 1024);
  r.b3 = *(const f16x8*)(p + 1536);
  return r;
}

__launch_bounds__(NTHR, 2)
__global__ void k_main(const float* __restrict__ x, const float* __restrict__ cb,
                       const unsigned char* __restrict__ cbH,
                       const float* __restrict__ cnorm,
                       double* __restrict__ lossAcc,
                       float* __restrict__ out)
{
  // A-plane: f16 resid, row m (64) x 512 k; 16B slot s=k/8 stored at
  // slot' = swap3(s) ^ (m&31) -> conflict-spread b128 reads and writes.
  __shared__ __align__(16) unsigned char Af[MPTS * DIM * 2];    // 64 KB
  __shared__ float          s1w[MPTS][8];
  __shared__ unsigned short id1w[MPTS][8];
  __shared__ unsigned short cand[MPTS][8][4];
  __shared__ unsigned char  ccnt[MPTS][8];
  __shared__ float          gmA[MPTS];
  __shared__ int            win0A[MPTS];
  __shared__ unsigned short idxs[MPTS][NUMQ];
  __shared__ double         lred[8];

  const int tid = threadIdx.x;
  const int cl  = tid & 63;
  const int w   = tid >> 6;          // wave 0..7; owns codes w*128..+127
  const int l31 = cl & 31;
  const int l5  = cl >> 5;           // k-group within wave
  const int wg  = blockIdx.x;

  // residual registers: thread owns point rp = tid>>3, dims rj*64 .. +64
  const int rp = tid >> 3;
  const int rj = tid & 7;
  const size_t gp = (size_t)wg * MPTS + rp;
  float4 r4[16];
  {
    const float4* xr = (const float4*)(x + gp * DIM + rj * 64);
    #pragma unroll
    for (int i = 0; i < 16; ++i) r4[i] = xr[i];
  }

  for (int q = 0; q < NUMQ; ++q) {
    // per-lane base into this q's chunk image (chunk stride 32 KB)
    const unsigned char* bq = cbH + ((size_t)q << 20) + (w << 12) + (l5 << 11) + (l31 << 4);

    // issue chunk 0/1 loads BEFORE the A-build so L3 latency hides under it
    BF s0 = loadB(bq);
    BF s1 = loadB(bq + CHUNK_BYTES);

    // ---- A-plane build: f16(resid), swizzled (verbatim R6)
    #pragma unroll
    for (int i = 0; i < 8; ++i) {
      float4 a = r4[2 * i], b = r4[2 * i + 1];
      f16x8 v;
      v[0] = (_Float16)a.x; v[1] = (_Float16)a.y; v[2] = (_Float16)a.z; v[3] = (_Float16)a.w;
      v[4] = (_Float16)b.x; v[5] = (_Float16)b.y; v[6] = (_Float16)b.z; v[7] = (_Float16)b.w;
      int sl = ((i << 3) | rj) ^ (rp & 31);            // swap3(j*8+i) ^ row
      *(f16x8*)(Af + rp * 1024 + (sl << 4)) = v;
    }
    __syncthreads();

    f32x16 acc[2][4];
    #pragma unroll
    for (int mt = 0; mt < 2; ++mt)
      #pragma unroll
      for (int nt = 0; nt < 4; ++nt)
        #pragma unroll
        for (int e = 0; e < 16; ++e) acc[mt][nt][e] = 0.0f;

    // ---- MFMA K-loop: no barriers, no LDS for B; 2-slot register ring,
    //      software-pipelined (issue ks+2 after ks consumed -> compiler
    //      emits counted vmcnt waits).
    #pragma unroll 1
    for (int kk = 0; kk < 16; ++kk) {
      const int ks = kk << 1;
      {
        const int s5 = (ks << 1) | l5;
        const int sf = ((((s5 & 7) << 3) | (s5 >> 3)) ^ l31) << 4;
        f16x8 a0 = *(const f16x8*)(Af + l31 * 1024 + sf);
        f16x8 a1 = *(const f16x8*)(Af + 32768 + l31 * 1024 + sf);
        __builtin_amdgcn_s_setprio(1);
        acc[0][0] = __builtin_amdgcn_mfma_f32_32x32x16_f16(a0, s0.b0, acc[0][0], 0, 0, 0);
        acc[0][1] = __builtin_amdgcn_mfma_f32_32x32x16_f16(a0, s0.b1, acc[0][1], 0, 0, 0);
        acc[0][2] = __builtin_amdgcn_mfma_f32_32x32x16_f16(a0, s0.b2, acc[0][2], 0, 0, 0);
        acc[0][3] = __builtin_amdgcn_mfma_f32_32x32x16_f16(a0, s0.b3, acc[0][3], 0, 0, 0);
        acc[1][0] = __builtin_amdgcn_mfma_f32_32x32x16_f16(a1, s0.b0, acc[1][0], 0, 0, 0);
        acc[1][1] = __builtin_amdgcn_mfma_f32_32x32x16_f16(a1, s0.b1, acc[1][1], 0, 0, 0);
        acc[1][2] = __builtin_amdgcn_mfma_f32_32x32x16_f16(a1, s0.b2, acc[1][2], 0, 0, 0);
        acc[1][3] = __builtin_amdgcn_mfma_f32_32x32x16_f16(a1, s0.b3, acc[1][3], 0, 0, 0);
        __builtin_amdgcn_s_setprio(0);
        if (ks + 2 < NCHUNK) s0 = loadB(bq + (size_t)(ks + 2) * CHUNK_BYTES);
      }
      {
        const int ks1 = ks + 1;
        const int s5 = (ks1 << 1) | l5;
        const int sf = ((((s5 & 7) << 3) | (s5 >> 3)) ^ l31) << 4;
        f16x8 a0 = *(const f16x8*)(Af + l31 * 1024 + sf);
        f16x8 a1 = *(const f16x8*)(Af + 32768 + l31 * 1024 + sf);
        __builtin_amdgcn_s_setprio(1);
        acc[0][0] = __builtin_amdgcn_mfma_f32_32x32x16_f16(a0, s1.b0, acc[0][0], 0, 0, 0);
        acc[0][1] = __builtin_amdgcn_mfma_f32_32x32x16_f16(a0, s1.b1, acc[0][1], 0, 0, 0);
        acc[0][2] = __builtin_amdgcn_mfma_f32_32x32x16_f16(a0, s1.b2, acc[0][2], 0, 0, 0);
        acc[0][3] = __builtin_amdgcn_mfma_f32_32x32x16_f16(a0, s1.b3, acc[0][3], 0, 0, 0);
        acc[1][0] = __builtin_amdgcn_mfma_f32_32x32x16_f16(a1, s1.b0, acc[1][0], 0, 0, 0);
        acc[1][1] = __builtin_amdgcn_mfma_f32_32x32x16_f16(a1, s1.b1, acc[1][1], 0, 0, 0);
        acc[1][2] = __builtin_amdgcn_mfma_f32_32x32x16_f16(a1, s1.b2, acc[1][2], 0, 0, 0);
        acc[1][3] = __builtin_amdgcn_mfma_f32_32x32x16_f16(a1, s1.b3, acc[1][3], 0, 0, 0);
        __builtin_amdgcn_s_setprio(0);
        if (ks1 + 2 < NCHUNK) s1 = loadB(bq + (size_t)(ks1 + 2) * CHUNK_BYTES);
      }
    }

    // ---- scores = -2*dot + ||c||^2 (approximate; f16-rounded inputs)
    {
      const float* cnq = cnorm + (q << 10) + (w << 7) + l31;
      const float cn0 = cnq[0], cn1 = cnq[32], cn2 = cnq[64], cn3 = cnq[96];
      #pragma unroll
      for (int mt = 0; mt < 2; ++mt) {
        acc[mt][0] = acc[mt][0] * -2.0f + cn0;
        acc[mt][1] = acc[mt][1] * -2.0f + cn1;
        acc[mt][2] = acc[mt][2] * -2.0f + cn2;
        acc[mt][3] = acc[mt][3] * -2.0f + cn3;
      }
    }

    // ---- pass 1: per-wave per-point top-1 (over this wave's 128 codes)
    // C/D layout 32x32: col = lane&31, row = (r&3)+8*(r>>2)+4*(lane>>5)
    #pragma unroll
    for (int mt = 0; mt < 2; ++mt)
      #pragma unroll
      for (int r = 0; r < 16; ++r) {
        float s = acc[mt][0][r]; int bi = l31;
        if (acc[mt][1][r] < s) { s = acc[mt][1][r]; bi = 32 + l31; }
        if (acc[mt][2][r] < s) { s = acc[mt][2][r]; bi = 64 + l31; }
        if (acc[mt][3][r] < s) { s = acc[mt][3][r]; bi = 96 + l31; }
        #pragma unroll
        for (int m = 1; m < 32; m <<= 1) {
          float os = __shfl_xor(s, m); int ob = __shfl_xor(bi, m);
          if (os < s || (os == s && ob < bi)) { s = os; bi = ob; }
        }
        if (l31 == 0) {
          int p = mt * 32 + (r & 3) + 8 * (r >> 2) + 4 * l5;
          s1w[p][w] = s; id1w[p][w] = (unsigned short)bi;
        }
      }
    __syncthreads();

    // ---- pass 2: global min + provisional winner per point
    if (tid < MPTS) {
      int p = tid;
      float bs = s1w[p][0]; int bi = id1w[p][0];
      #pragma unroll
      for (int ww = 1; ww < 8; ++ww) {
        float s = s1w[p][ww];
        if (s < bs) { bs = s; bi = ww * 128 + id1w[p][ww]; }
      }
      gmA[p] = bs; win0A[p] = bi;
    }
    __syncthreads();

    // ---- pass 3: ballot candidates within margin of global min
    //      (margin 1.5 vs f16 score error sigma~0.03; proven R4/R6)
    #pragma unroll
    for (int mt = 0; mt < 2; ++mt)
      #pragma unroll
      for (int r = 0; r < 16; ++r) {
        const int p0 = mt * 32 + (r & 3) + 8 * (r >> 2);
        const float g0 = gmA[p0], g1 = gmA[p0 + 4];
        const float lim0 = g0 + 1.5f + 1e-4f * fabsf(g0);
        const float lim1 = g1 + 1.5f + 1e-4f * fabsf(g1);
        const float lim = l5 ? lim1 : lim0;
        unsigned long long b0 = __ballot(acc[mt][0][r] <= lim);
        unsigned long long b1 = __ballot(acc[mt][1][r] <= lim);
        unsigned long long b2 = __ballot(acc[mt][2][r] <= lim);
        unsigned long long b3 = __ballot(acc[mt][3][r] <= lim);
        if (cl == 0 || cl == 32) {
          const int p = p0 + (cl >> 3);
          unsigned short* cd = &cand[p][w][0];
          unsigned m0 = (cl == 0) ? (unsigned)b0 : (unsigned)(b0 >> 32);
          unsigned m1 = (cl == 0) ? (unsigned)b1 : (unsigned)(b1 >> 32);
          unsigned m2 = (cl == 0) ? (unsigned)b2 : (unsigned)(b2 >> 32);
          unsigned m3 = (cl == 0) ? (unsigned)b3 : (unsigned)(b3 >> 32);
          int n = 0;
          while (m0 && n < 4) { int bt = __builtin_ctz(m0); m0 &= m0 - 1; cd[n++] = (unsigned short)(bt); }
          while (m1 && n < 4) { int bt = __builtin_ctz(m1); m1 &= m1 - 1; cd[n++] = (unsigned short)(32 + bt); }
          while (m2 && n < 4) { int bt = __builtin_ctz(m2); m2 &= m2 - 1; cd[n++] = (unsigned short)(64 + bt); }
          while (m3 && n < 4) { int bt = __builtin_ctz(m3); m3 &= m3 - 1; cd[n++] = (unsigned short)(96 + bt); }
          ccnt[p][w] = (unsigned char)n;
        }
      }
    __syncthreads();

    // ---- pass 4: refinement tiers (wave w owns points w*8..w*8+7; their
    //      fp32 residual lives in this wave's r4 registers, 8 lanes/point)
    #pragma unroll 1
    for (int pp = 0; pp < 8; ++pp) {
      const int p = (w << 3) + pp;
      int tot = 0;
      #pragma unroll
      for (int ww = 0; ww < 8; ++ww) tot += ccnt[p][ww];
      int winner;
      if (tot <= 1) {
        winner = win0A[p];
      } else {
        const size_t gpp = (size_t)wg * MPTS + p;
        // tier 1: fp64 dot vs exact fp32 residual (in regs)
        double bs = 1.0e300, bs2 = 1.0e300; int bi = 0x7FFFFFFF;
        #pragma unroll 1
        for (int ww = 0; ww < 8; ++ww) {
          const int nn = ccnt[p][ww];
          #pragma unroll 1
          for (int si = 0; si < nn; ++si) {
            const int cc = ww * 128 + cand[p][ww][si];
            const float4* cr = (const float4*)(cb + ((size_t)q * CODES + cc) * DIM + (cl & 7) * 64);
            double dt = 0.0, cs = 0.0;
            #pragma unroll
            for (int i = 0; i < 16; ++i) {
              float4 cv = cr[i];
              dt += (double)r4[i].x * cv.x + (double)r4[i].y * cv.y
                  + (double)r4[i].z * cv.z + (double)r4[i].w * cv.w;
              cs += (double)cv.x * cv.x + (double)cv.y * cv.y
                  + (double)cv.z * cv.z + (double)cv.w * cv.w;
            }
            #pragma unroll
            for (int m = 1; m < 8; m <<= 1) { dt += __shfl_xor(dt, m); cs += __shfl_xor(cs, m); }
            double dtb = __shfl(dt, pp * 8), csb = __shfl(cs, pp * 8);
            double s = -2.0 * dtb + csb;
            if (s < bs) { bs2 = bs; bs = s; bi = cc; }
            else if (s < bs2) { bs2 = s; }
          }
        }
        // tier 2: exact fp64 chain rebuild from x (rare: <1e-3 gap)
        if (bs2 - bs <= 1e-3 + 1e-6 * fabs(bs)) {
          bs = 1.0e300; bi = 0x7FFFFFFF;
          const float4* xr2 = (const float4*)(x + gpp * DIM + (cl & 7) * 64);
          #pragma unroll 1
          for (int ww = 0; ww < 8; ++ww) {
            const int nn = ccnt[p][ww];
            #pragma unroll 1
            for (int si = 0; si < nn; ++si) {
              const int cc = ww * 128 + cand[p][ww][si];
              const float4* cr = (const float4*)(cb + ((size_t)q * CODES + cc) * DIM + (cl & 7) * 64);
              double dt = 0.0, cs = 0.0;
              #pragma unroll 1
              for (int i = 0; i < 16; ++i) {
                float4 xv = xr2[i];
                double rhx = xv.x, rhy = xv.y, rhz = xv.z, rhw = xv.w;
                #pragma unroll 1
                for (int t2 = 0; t2 < q; ++t2) {
                  const float4* qr = (const float4*)(cb + ((size_t)t2 * CODES + idxs[p][t2]) * DIM + (cl & 7) * 64);
                  float4 qv = qr[i];
                  rhx -= (double)qv.x; rhy -= (double)qv.y;
                  rhz -= (double)qv.z; rhw -= (double)qv.w;
                }
                float4 cv = cr[i];
                dt += rhx * cv.x + rhy * cv.y + rhz * cv.z + rhw * cv.w;
                cs += (double)cv.x * cv.x + (double)cv.y * cv.y
                    + (double)cv.z * cv.z + (double)cv.w * cv.w;
              }
              #pragma unroll
              for (int m = 1; m < 8; m <<= 1) { dt += __shfl_xor(dt, m); cs += __shfl_xor(cs, m); }
              double dtb = __shfl(dt, pp * 8), csb = __shfl(cs, pp * 8);
              double s = -2.0 * dtb + csb;
              if (s < bs || (s == bs && cc < bi)) { bs = s; bi = cc; }
            }
          }
        }
        winner = bi;
      }
      if (cl == 0) idxs[p][q] = (unsigned short)winner;
    }
    __syncthreads();

    // ---- pass 5: residual update (exact fp32 chain) + commit loss (fp64)
    {
      const int win = idxs[rp][q];
      const float4* cr = (const float4*)(cb + ((size_t)q * CODES + win) * DIM + rj * 64);
      double ls = 0.0;
      #pragma unroll
      for (int i = 0; i < 16; ++i) {
        float4 cv = cr[i];
        float dx = cv.x - r4[i].x, dy = cv.y - r4[i].y;
        float dz = cv.z - r4[i].z, dw = cv.w - r4[i].w;
        ls += (double)dx * dx + (double)dy * dy + (double)dz * dz + (double)dw * dw;
        r4[i].x -= cv.x; r4[i].y -= cv.y; r4[i].z -= cv.z; r4[i].w -= cv.w;
      }
      #pragma unroll
      for (int m = 1; m < 64; m <<= 1) ls += __shfl_xor(ls, m);
      if (cl == 0) lred[w] = ls;
      __syncthreads();
      if (tid == 0) {
        double t = lred[0] + lred[1] + lred[2] + lred[3]
                 + lred[4] + lred[5] + lred[6] + lred[7];
        atomicAdd(lossAcc + q, t);
      }
      __syncthreads();
    }
  } // q

  // ---- outputs: quantized = x - resid_final; indices as float
  {
    const float4* xr = (const float4*)(x + gp * DIM + rj * 64);
    float4* orow = (float4*)(out + gp * DIM + rj * 64);
    #pragma unroll
    for (int i = 0; i < 16; ++i) {
      float4 xv = xr[i];
      float4 o;
      o.x = xv.x - r4[i].x; o.y = xv.y - r4[i].y;
      o.z = xv.z - r4[i].z; o.w = xv.w - r4[i].w;
      orow[i] = o;
    }
  }
  if (tid < MPTS) {
    float* ob = out + OUT_IDX + ((size_t)wg * MPTS + tid) * NUMQ;
    #pragma unroll
    for (int j = 0; j < NUMQ; ++j) ob[j] = (float)idxs[tid][j];
  }
}

__global__ void k_fin(const double* __restrict__ loss, float* __restrict__ out) {
  int t = threadIdx.x;
  if (t < NUMQ)
    out[OUT_LOSS + t] = (float)(loss[t] / (double)((size_t)BATCH * SEQ * DIM));
}

extern "C" void kernel_launch(void* const* d_in, const int* in_sizes, int n_in,
                              void* d_out, int out_size, void* d_ws, size_t ws_size,
                              hipStream_t stream) {
  (void)in_sizes; (void)n_in; (void)out_size; (void)ws_size;
  const float* x  = (const float*)d_in[0];
  const float* cb = (const float*)d_in[1];
  float* out = (float*)d_out;
  char* ws = (char*)d_ws;
  double* loss = (double*)(ws + WS_LOSS);
  float* cnorm = (float*)(ws + WS_CNORM);
  unsigned char* cbH = (unsigned char*)(ws + WS_CBH);   // 8.39 MB

  k_zero<<<1, 64, 0, stream>>>(loss);
  k_cnorm<<<NUMQ * CODES / 256, 256, 0, stream>>>(cb, cnorm);
  k_prep<<<NUMQ * NCHUNK * CHUNK_BYTES / 8 / 256, 256, 0, stream>>>(cb, cbH);
  k_main<<<NWG, NTHR, 0, stream>>>(x, cb, cbH, cnorm, loss, out);
  k_fin<<<1, 64, 0, stream>>>(loss, out);
}

// Round 6
// 543.110 us; speedup vs baseline: 1.3414x; 1.1288x over previous
//
#include <hip/hip_runtime.h>
#include <cstdint>
#include <cstddef>

// ---------------------------------------------------------------------------
// Residual VQ (SoundStream Alg.1) on MI355X — R9: epilogue diet.
// R5-R8 nulls: barriers, occupancy, buffer depth, staging mechanism all
// varied; wall pinned ~550-570 -> K-loop exonerated. Invariant blob ~390 us
// = passes 1-5 (SQ_LDS_BANK_CONFLICT bit-identical 231065 across R4/R6/R8).
// R9 cuts the dependent chains:
//  - pass1: score-only fminf shfl ladder + ballot/ctz id recovery (tie-break
//    change provably safe: any fp32 tie => >=2 candidates => exact tier)
//  - pass4: 8-lane-group parallel refinement (8x), group owns its point's
//    exact fp32 residual in-lane; no redundant 64-lane recompute
//  - fp64 code norms PRECOMPUTED (k_cnormd) -> tier chains halved; dt via
//    4 independent partials (ILP)
//  - pass5 loss: 2-way ILP partials
// K-loop, A-plane, margins, tier thresholds, exactness guarantees verbatim
// R8 (absmax 0.03125 proven).
// ---------------------------------------------------------------------------

#define BATCH 8
#define SEQ   2048
#define DIM   512
#define NUMQ  8
#define CODES 1024
#define NPTS  (BATCH*SEQ)            // 16384
#define MPTS  64                     // points per workgroup
#define NWG   (NPTS/MPTS)            // 256 = 1 WG per CU
#define NTHR  512                    // 8 waves
#define NCHUNK 32                    // K-steps of 16 per quantizer
#define CHUNK_BYTES 32768            // per global chunk: [w:8][g:2][c:128][j:8 f16]

#define OUT_IDX   (BATCH*SEQ*DIM)             // 8388608
#define OUT_LOSS  (OUT_IDX + BATCH*SEQ*NUMQ)  // 8519680

#define WS_LOSS   0                           // 8 doubles
#define WS_CNORM  1024                        // 8192 floats
#define WS_CBH    40960                       // f16 chunk images, 8.39 MB
#define WS_CNORMD (WS_CBH + NUMQ*NCHUNK*CHUNK_BYTES)  // 8192 doubles

typedef _Float16 f16x8  __attribute__((ext_vector_type(8)));
typedef _Float16 f16x4  __attribute__((ext_vector_type(4)));
typedef float    f32x16 __attribute__((ext_vector_type(16)));

__global__ void k_zero(double* loss) {
  if (threadIdx.x < NUMQ) loss[threadIdx.x] = 0.0;
}

// per-code squared norm (fp32; only feeds the approximate scores)
__global__ void k_cnorm(const float* __restrict__ cb, float* __restrict__ cnorm) {
  int r = blockIdx.x * blockDim.x + threadIdx.x;      // 0..8191
  const float* row = cb + (size_t)r * DIM;
  float s = 0.f;
  for (int d = 0; d < DIM; d += 4) {
    float4 v = *(const float4*)(row + d);
    s += v.x * v.x + v.y * v.y + v.z * v.z + v.w * v.w;
  }
  cnorm[r] = s;
}

// per-code squared norm, fp64 (feeds the exact refinement tiers)
__global__ void k_cnormd(const float* __restrict__ cb, double* __restrict__ cnd) {
  int r = blockIdx.x * blockDim.x + threadIdx.x;      // 0..8191
  const float4* row = (const float4*)(cb + (size_t)r * DIM);
  double d0 = 0, d1 = 0, d2 = 0, d3 = 0;
  for (int i = 0; i < 128; i += 4) {
    float4 a = row[i], b = row[i + 1], c = row[i + 2], d = row[i + 3];
    d0 += (double)a.x * a.x + (double)a.y * a.y + (double)a.z * a.z + (double)a.w * a.w;
    d1 += (double)b.x * b.x + (double)b.y * b.y + (double)b.z * b.z + (double)b.w * b.w;
    d2 += (double)c.x * c.x + (double)c.y * c.y + (double)c.z * c.z + (double)c.w * c.w;
    d3 += (double)d.x * d.x + (double)d.y * d.y + (double)d.z * d.z + (double)d.w * d.w;
  }
  cnd[r] = (d0 + d1) + (d2 + d3);
}

// Build f16 codebook chunk images, PER-WAVE sub-chunks (verbatim R6):
//   chunk n=(q,ks): 8 sub-chunks of 4 KB, one per wave w (codes w*128..+127)
//   sub-chunk layout [g:2][c:128][j:8 f16]; element = cb[q][w*128+c][ks*16+g*8+j]
__global__ void k_prep(const float* __restrict__ cb, unsigned char* __restrict__ cbH) {
  unsigned u = blockIdx.x * blockDim.x + threadIdx.x;   // 0..1048575 (8B units)
  unsigned h  = u & 1;                 // j-half (4 f16)
  unsigned v  = u >> 1;                // 16B granule
  unsigned c  = v & 127;
  unsigned g  = (v >> 7) & 1;
  unsigned w  = (v >> 8) & 7;
  unsigned ks = (v >> 11) & 31;
  unsigned q  = v >> 16;
  unsigned code = (w << 7) | c;
  unsigned k = ks * 16 + g * 8 + h * 4;
  float4 val = *(const float4*)(cb + ((size_t)((q << 10) | code)) * DIM + k);
  f16x4 o;
  o[0] = (_Float16)val.x; o[1] = (_Float16)val.y;
  o[2] = (_Float16)val.z; o[3] = (_Float16)val.w;
  *(f16x4*)(cbH + (size_t)u * 8) = o;
}

// one chunk's 4 B-fragments for this lane (4x global_load_dwordx4, coalesced)
struct BF { f16x8 b0, b1, b2, b3; };
__device__ __forceinline__ BF loadB(const unsigned char* __restrict__ p) {
  BF r;
  r.b0 = *(const f16x8*)(p);
  r.b1 = *(const f16x8*)(p + 512);
  r.b2 = *(const f16x8*)(p + 1024);
  r.b3 = *(const f16x8*)(p + 1536);
  return r;
}

__launch_bounds__(NTHR, 2)
__global__ void k_main(const float* __restrict__ x, const float* __restrict__ cb,
                       const unsigned char* __restrict__ cbH,
                       const float* __restrict__ cnorm,
                       const double* __restrict__ cnormd,
                       double* __restrict__ lossAcc,
                       float* __restrict__ out)
{
  // A-plane: f16 resid, row m (64) x 512 k; 16B slot s=k/8 stored at
  // slot' = swap3(s) ^ (m&31) -> conflict-spread b128 reads and writes.
  __shared__ __align__(16) unsigned char Af[MPTS * DIM * 2];    // 64 KB
  __shared__ float          s1w[MPTS][8];
  __shared__ unsigned short id1w[MPTS][8];
  __shared__ unsigned short cand[MPTS][8][4];
  __shared__ unsigned char  ccnt[MPTS][8];
  __shared__ float          gmA[MPTS];
  __shared__ int            win0A[MPTS];
  __shared__ unsigned short idxs[MPTS][NUMQ];
  __shared__ double         lred[8];

  const int tid = threadIdx.x;
  const int cl  = tid & 63;
  const int w   = tid >> 6;          // wave 0..7; owns codes w*128..+127
  const int l31 = cl & 31;
  const int l5  = cl >> 5;           // k-group within wave
  const int wg  = blockIdx.x;

  // residual registers: thread owns point rp = tid>>3, dims rj*64 .. +64
  const int rp = tid >> 3;
  const int rj = tid & 7;
  const size_t gp = (size_t)wg * MPTS + rp;
  float4 r4[16];
  {
    const float4* xr = (const float4*)(x + gp * DIM + rj * 64);
    #pragma unroll
    for (int i = 0; i < 16; ++i) r4[i] = xr[i];
  }

  for (int q = 0; q < NUMQ; ++q) {
    // per-lane base into this q's chunk image (chunk stride 32 KB)
    const unsigned char* bq = cbH + ((size_t)q << 20) + (w << 12) + (l5 << 11) + (l31 << 4);

    // issue chunk 0/1 loads BEFORE the A-build so L3 latency hides under it
    BF s0 = loadB(bq);
    BF s1 = loadB(bq + CHUNK_BYTES);

    // ---- A-plane build: f16(resid), swizzled (verbatim R6/R8)
    #pragma unroll
    for (int i = 0; i < 8; ++i) {
      float4 a = r4[2 * i], b = r4[2 * i + 1];
      f16x8 v;
      v[0] = (_Float16)a.x; v[1] = (_Float16)a.y; v[2] = (_Float16)a.z; v[3] = (_Float16)a.w;
      v[4] = (_Float16)b.x; v[5] = (_Float16)b.y; v[6] = (_Float16)b.z; v[7] = (_Float16)b.w;
      int sl = ((i << 3) | rj) ^ (rp & 31);            // swap3(j*8+i) ^ row
      *(f16x8*)(Af + rp * 1024 + (sl << 4)) = v;
    }
    __syncthreads();

    f32x16 acc[2][4];
    #pragma unroll
    for (int mt = 0; mt < 2; ++mt)
      #pragma unroll
      for (int nt = 0; nt < 4; ++nt)
        #pragma unroll
        for (int e = 0; e < 16; ++e) acc[mt][nt][e] = 0.0f;

    // ---- MFMA K-loop: no barriers, no LDS for B; 2-slot register ring
    //      (verbatim R8)
    #pragma unroll 1
    for (int kk = 0; kk < 16; ++kk) {
      const int ks = kk << 1;
      {
        const int s5 = (ks << 1) | l5;
        const int sf = ((((s5 & 7) << 3) | (s5 >> 3)) ^ l31) << 4;
        f16x8 a0 = *(const f16x8*)(Af + l31 * 1024 + sf);
        f16x8 a1 = *(const f16x8*)(Af + 32768 + l31 * 1024 + sf);
        __builtin_amdgcn_s_setprio(1);
        acc[0][0] = __builtin_amdgcn_mfma_f32_32x32x16_f16(a0, s0.b0, acc[0][0], 0, 0, 0);
        acc[0][1] = __builtin_amdgcn_mfma_f32_32x32x16_f16(a0, s0.b1, acc[0][1], 0, 0, 0);
        acc[0][2] = __builtin_amdgcn_mfma_f32_32x32x16_f16(a0, s0.b2, acc[0][2], 0, 0, 0);
        acc[0][3] = __builtin_amdgcn_mfma_f32_32x32x16_f16(a0, s0.b3, acc[0][3], 0, 0, 0);
        acc[1][0] = __builtin_amdgcn_mfma_f32_32x32x16_f16(a1, s0.b0, acc[1][0], 0, 0, 0);
        acc[1][1] = __builtin_amdgcn_mfma_f32_32x32x16_f16(a1, s0.b1, acc[1][1], 0, 0, 0);
        acc[1][2] = __builtin_amdgcn_mfma_f32_32x32x16_f16(a1, s0.b2, acc[1][2], 0, 0, 0);
        acc[1][3] = __builtin_amdgcn_mfma_f32_32x32x16_f16(a1, s0.b3, acc[1][3], 0, 0, 0);
        __builtin_amdgcn_s_setprio(0);
        if (ks + 2 < NCHUNK) s0 = loadB(bq + (size_t)(ks + 2) * CHUNK_BYTES);
      }
      {
        const int ks1 = ks + 1;
        const int s5 = (ks1 << 1) | l5;
        const int sf = ((((s5 & 7) << 3) | (s5 >> 3)) ^ l31) << 4;
        f16x8 a0 = *(const f16x8*)(Af + l31 * 1024 + sf);
        f16x8 a1 = *(const f16x8*)(Af + 32768 + l31 * 1024 + sf);
        __builtin_amdgcn_s_setprio(1);
        acc[0][0] = __builtin_amdgcn_mfma_f32_32x32x16_f16(a0, s1.b0, acc[0][0], 0, 0, 0);
        acc[0][1] = __builtin_amdgcn_mfma_f32_32x32x16_f16(a0, s1.b1, acc[0][1], 0, 0, 0);
        acc[0][2] = __builtin_amdgcn_mfma_f32_32x32x16_f16(a0, s1.b2, acc[0][2], 0, 0, 0);
        acc[0][3] = __builtin_amdgcn_mfma_f32_32x32x16_f16(a0, s1.b3, acc[0][3], 0, 0, 0);
        acc[1][0] = __builtin_amdgcn_mfma_f32_32x32x16_f16(a1, s1.b0, acc[1][0], 0, 0, 0);
        acc[1][1] = __builtin_amdgcn_mfma_f32_32x32x16_f16(a1, s1.b1, acc[1][1], 0, 0, 0);
        acc[1][2] = __builtin_amdgcn_mfma_f32_32x32x16_f16(a1, s1.b2, acc[1][2], 0, 0, 0);
        acc[1][3] = __builtin_amdgcn_mfma_f32_32x32x16_f16(a1, s1.b3, acc[1][3], 0, 0, 0);
        __builtin_amdgcn_s_setprio(0);
        if (ks1 + 2 < NCHUNK) s1 = loadB(bq + (size_t)(ks1 + 2) * CHUNK_BYTES);
      }
    }

    // ---- scores = -2*dot + ||c||^2 (approximate; f16-rounded inputs)
    {
      const float* cnq = cnorm + (q << 10) + (w << 7) + l31;
      const float cn0 = cnq[0], cn1 = cnq[32], cn2 = cnq[64], cn3 = cnq[96];
      #pragma unroll
      for (int mt = 0; mt < 2; ++mt) {
        acc[mt][0] = acc[mt][0] * -2.0f + cn0;
        acc[mt][1] = acc[mt][1] * -2.0f + cn1;
        acc[mt][2] = acc[mt][2] * -2.0f + cn2;
        acc[mt][3] = acc[mt][3] * -2.0f + cn3;
      }
    }

    // ---- pass 1: per-wave per-point top-1, score-only ladder + ballot id.
    // C/D layout 32x32: col = lane&31, row = (r&3)+8*(r>>2)+4*(lane>>5)
    #pragma unroll
    for (int mt = 0; mt < 2; ++mt)
      #pragma unroll
      for (int r = 0; r < 16; ++r) {
        float s = acc[mt][0][r]; int bi = l31;
        if (acc[mt][1][r] < s) { s = acc[mt][1][r]; bi = 32 + l31; }
        if (acc[mt][2][r] < s) { s = acc[mt][2][r]; bi = 64 + l31; }
        if (acc[mt][3][r] < s) { s = acc[mt][3][r]; bi = 96 + l31; }
        float smin = s;
        #pragma unroll
        for (int m = 1; m < 32; m <<= 1) smin = fminf(smin, __shfl_xor(smin, m));
        unsigned long long bm = __ballot(s == smin);
        unsigned half = l5 ? (unsigned)(bm >> 32) : (unsigned)bm;
        int first = __builtin_ctz(half) + (l5 << 5);
        int id = __shfl(bi, first);
        if (l31 == 0) {
          int p = mt * 32 + (r & 3) + 8 * (r >> 2) + 4 * l5;
          s1w[p][w] = smin; id1w[p][w] = (unsigned short)id;
        }
      }
    __syncthreads();

    // ---- pass 2: global min + provisional winner per point
    if (tid < MPTS) {
      int p = tid;
      float bs = s1w[p][0]; int bi = id1w[p][0];
      #pragma unroll
      for (int ww = 1; ww < 8; ++ww) {
        float s = s1w[p][ww];
        if (s < bs) { bs = s; bi = ww * 128 + id1w[p][ww]; }
      }
      gmA[p] = bs; win0A[p] = bi;
    }
    __syncthreads();

    // ---- pass 3: ballot candidates within margin of global min
    //      (margin 1.5 vs f16 score error sigma~0.03; proven R4-R8)
    #pragma unroll
    for (int mt = 0; mt < 2; ++mt)
      #pragma unroll
      for (int r = 0; r < 16; ++r) {
        const int p0 = mt * 32 + (r & 3) + 8 * (r >> 2);
        const float g0 = gmA[p0], g1 = gmA[p0 + 4];
        const float lim0 = g0 + 1.5f + 1e-4f * fabsf(g0);
        const float lim1 = g1 + 1.5f + 1e-4f * fabsf(g1);
        const float lim = l5 ? lim1 : lim0;
        unsigned long long b0 = __ballot(acc[mt][0][r] <= lim);
        unsigned long long b1 = __ballot(acc[mt][1][r] <= lim);
        unsigned long long b2 = __ballot(acc[mt][2][r] <= lim);
        unsigned long long b3 = __ballot(acc[mt][3][r] <= lim);
        if (cl == 0 || cl == 32) {
          const int p = p0 + (cl >> 3);
          unsigned short* cd = &cand[p][w][0];
          unsigned m0 = (cl == 0) ? (unsigned)b0 : (unsigned)(b0 >> 32);
          unsigned m1 = (cl == 0) ? (unsigned)b1 : (unsigned)(b1 >> 32);
          unsigned m2 = (cl == 0) ? (unsigned)b2 : (unsigned)(b2 >> 32);
          unsigned m3 = (cl == 0) ? (unsigned)b3 : (unsigned)(b3 >> 32);
          int n = 0;
          while (m0 && n < 4) { int bt = __builtin_ctz(m0); m0 &= m0 - 1; cd[n++] = (unsigned short)(bt); }
          while (m1 && n < 4) { int bt = __builtin_ctz(m1); m1 &= m1 - 1; cd[n++] = (unsigned short)(32 + bt); }
          while (m2 && n < 4) { int bt = __builtin_ctz(m2); m2 &= m2 - 1; cd[n++] = (unsigned short)(64 + bt); }
          while (m3 && n < 4) { int bt = __builtin_ctz(m3); m3 &= m3 - 1; cd[n++] = (unsigned short)(96 + bt); }
          ccnt[p][w] = (unsigned char)n;
        }
      }
    __syncthreads();

    // ---- pass 4: refinement tiers, 8-lane-GROUP PARALLEL (new in R9).
    //      Group g = cl>>3 of wave w refines point p = w*8+g; that point's
    //      exact fp32 residual lives in exactly these lanes (rp==p).
    {
      const int g  = cl >> 3;
      const int gl = cl & 7;
      const int p  = (w << 3) + g;          // == rp
      int tot = 0;
      #pragma unroll
      for (int ww = 0; ww < 8; ++ww) tot += ccnt[p][ww];
      int winner = win0A[p];
      // wave-uniform upper bound on candidate count
      int mtot = tot;
      #pragma unroll
      for (int m = 1; m < 64; m <<= 1) { int o = __shfl_xor(mtot, m); if (o > mtot) mtot = o; }
      if (mtot > 1) {
        const size_t gpp = gp;              // == wg*MPTS + p for these lanes
        double bs = 1.0e300, bs2 = 1.0e300; int bi = 0x7FFFFFFF;
        #pragma unroll 1
        for (int k = 0; k < mtot; ++k) {
          int cc = -1;
          if (tot > 1 && k < tot) {
            int rem = k, ww = 0;
            #pragma unroll 1
            for (; ww < 7; ++ww) { int nn = ccnt[p][ww]; if (rem < nn) break; rem -= nn; }
            cc = ww * 128 + cand[p][ww][rem];
          }
          double dt = 0.0;
          if (cc >= 0) {
            // tier 1: fp64 dot vs exact fp32 residual (in regs), 4-way ILP
            const float4* cr = (const float4*)(cb + ((size_t)q * CODES + cc) * DIM + gl * 64);
            double d0 = 0, d1 = 0, d2 = 0, d3 = 0;
            #pragma unroll
            for (int i = 0; i < 16; i += 4) {
              float4 c0 = cr[i], c1 = cr[i + 1], c2 = cr[i + 2], c3 = cr[i + 3];
              d0 += (double)r4[i].x * c0.x + (double)r4[i].y * c0.y
                  + (double)r4[i].z * c0.z + (double)r4[i].w * c0.w;
              d1 += (double)r4[i + 1].x * c1.x + (double)r4[i + 1].y * c1.y
                  + (double)r4[i + 1].z * c1.z + (double)r4[i + 1].w * c1.w;
              d2 += (double)r4[i + 2].x * c2.x + (double)r4[i + 2].y * c2.y
                  + (double)r4[i + 2].z * c2.z + (double)r4[i + 2].w * c2.w;
              d3 += (double)r4[i + 3].x * c3.x + (double)r4[i + 3].y * c3.y
                  + (double)r4[i + 3].z * c3.z + (double)r4[i + 3].w * c3.w;
            }
            dt = (d0 + d1) + (d2 + d3);
          }
          #pragma unroll
          for (int m = 1; m < 8; m <<= 1) dt += __shfl_xor(dt, m);
          if (cc >= 0) {
            double s = -2.0 * dt + cnormd[(q << 10) + cc];
            if (s < bs) { bs2 = bs; bs = s; bi = cc; }
            else if (s < bs2) { bs2 = s; }
          }
        }
        // tier 2: exact fp64 chain rebuild from x (rare: <1e-3 gap)
        if (tot > 1 && bs2 - bs <= 1e-3 + 1e-6 * fabs(bs)) {
          bs = 1.0e300; bi = 0x7FFFFFFF;
          const float4* xr2 = (const float4*)(x + gpp * DIM + gl * 64);
          #pragma unroll 1
          for (int k = 0; k < tot; ++k) {
            int rem = k, ww = 0;
            #pragma unroll 1
            for (; ww < 7; ++ww) { int nn = ccnt[p][ww]; if (rem < nn) break; rem -= nn; }
            const int cc = ww * 128 + cand[p][ww][rem];
            const float4* cr = (const float4*)(cb + ((size_t)q * CODES + cc) * DIM + gl * 64);
            double dt = 0.0;
            #pragma unroll 1
            for (int i = 0; i < 16; ++i) {
              float4 xv = xr2[i];
              double rhx = xv.x, rhy = xv.y, rhz = xv.z, rhw = xv.w;
              #pragma unroll 1
              for (int t2 = 0; t2 < q; ++t2) {
                const float4* qr = (const float4*)(cb + ((size_t)t2 * CODES + idxs[p][t2]) * DIM + gl * 64);
                float4 qv = qr[i];
                rhx -= (double)qv.x; rhy -= (double)qv.y;
                rhz -= (double)qv.z; rhw -= (double)qv.w;
              }
              float4 cv = cr[i];
              dt += rhx * cv.x + rhy * cv.y + rhz * cv.z + rhw * cv.w;
            }
            #pragma unroll
            for (int m = 1; m < 8; m <<= 1) dt += __shfl_xor(dt, m);
            double s = -2.0 * dt + cnormd[(q << 10) + cc];
            if (s < bs || (s == bs && cc < bi)) { bs = s; bi = cc; }
          }
        }
        if (tot > 1) winner = bi;
      }
      if (gl == 0) idxs[p][q] = (unsigned short)winner;
    }
    __syncthreads();

    // ---- pass 5: residual update (exact fp32 chain) + commit loss (fp64,
    //      2-way ILP partials)
    {
      const int win = idxs[rp][q];
      const float4* cr = (const float4*)(cb + ((size_t)q * CODES + win) * DIM + rj * 64);
      double ls0 = 0.0, ls1 = 0.0;
      #pragma unroll
      for (int i = 0; i < 16; i += 2) {
        float4 c0 = cr[i], c1 = cr[i + 1];
        float dx0 = c0.x - r4[i].x, dy0 = c0.y - r4[i].y;
        float dz0 = c0.z - r4[i].z, dw0 = c0.w - r4[i].w;
        ls0 += (double)dx0 * dx0 + (double)dy0 * dy0 + (double)dz0 * dz0 + (double)dw0 * dw0;
        r4[i].x -= c0.x; r4[i].y -= c0.y; r4[i].z -= c0.z; r4[i].w -= c0.w;
        float dx1 = c1.x - r4[i + 1].x, dy1 = c1.y - r4[i + 1].y;
        float dz1 = c1.z - r4[i + 1].z, dw1 = c1.w - r4[i + 1].w;
        ls1 += (double)dx1 * dx1 + (double)dy1 * dy1 + (double)dz1 * dz1 + (double)dw1 * dw1;
        r4[i + 1].x -= c1.x; r4[i + 1].y -= c1.y; r4[i + 1].z -= c1.z; r4[i + 1].w -= c1.w;
      }
      double ls = ls0 + ls1;
      #pragma unroll
      for (int m = 1; m < 64; m <<= 1) ls += __shfl_xor(ls, m);
      if (cl == 0) lred[w] = ls;
      __syncthreads();
      if (tid == 0) {
        double t = lred[0] + lred[1] + lred[2] + lred[3]
                 + lred[4] + lred[5] + lred[6] + lred[7];
        atomicAdd(lossAcc + q, t);
      }
      __syncthreads();
    }
  } // q

  // ---- outputs: quantized = x - resid_final; indices as float
  {
    const float4* xr = (const float4*)(x + gp * DIM + rj * 64);
    float4* orow = (float4*)(out + gp * DIM + rj * 64);
    #pragma unroll
    for (int i = 0; i < 16; ++i) {
      float4 xv = xr[i];
      float4 o;
      o.x = xv.x - r4[i].x; o.y = xv.y - r4[i].y;
      o.z = xv.z - r4[i].z; o.w = xv.w - r4[i].w;
      orow[i] = o;
    }
  }
  if (tid < MPTS) {
    float* ob = out + OUT_IDX + ((size_t)wg * MPTS + tid) * NUMQ;
    #pragma unroll
    for (int j = 0; j < NUMQ; ++j) ob[j] = (float)idxs[tid][j];
  }
}

__global__ void k_fin(const double* __restrict__ loss, float* __restrict__ out) {
  int t = threadIdx.x;
  if (t < NUMQ)
    out[OUT_LOSS + t] = (float)(loss[t] / (double)((size_t)BATCH * SEQ * DIM));
}

extern "C" void kernel_launch(void* const* d_in, const int* in_sizes, int n_in,
                              void* d_out, int out_size, void* d_ws, size_t ws_size,
                              hipStream_t stream) {
  (void)in_sizes; (void)n_in; (void)out_size; (void)ws_size;
  const float* x  = (const float*)d_in[0];
  const float* cb = (const float*)d_in[1];
  float* out = (float*)d_out;
  char* ws = (char*)d_ws;
  double* loss = (double*)(ws + WS_LOSS);
  float* cnorm = (float*)(ws + WS_CNORM);
  unsigned char* cbH = (unsigned char*)(ws + WS_CBH);   // 8.39 MB
  double* cnormd = (double*)(ws + WS_CNORMD);           // 64 KB

  k_zero<<<1, 64, 0, stream>>>(loss);
  k_cnorm<<<NUMQ * CODES / 256, 256, 0, stream>>>(cb, cnorm);
  k_cnormd<<<NUMQ * CODES / 256, 256, 0, stream>>>(cb, cnormd);
  k_prep<<<NUMQ * NCHUNK * CHUNK_BYTES / 8 / 256, 256, 0, stream>>>(cb, cbH);
  k_main<<<NWG, NTHR, 0, stream>>>(x, cb, cbH, cnorm, cnormd, loss, out);
  k_fin<<<1, 64, 0, stream>>>(loss, out);
}